// Round 18
// baseline (178.947 us; speedup 1.0000x reference)
//
#include <hip/hip_runtime.h>
#include <hip/hip_fp16.h>

#define N_NODES 50000
#define E_EDGES 800000
#define SCAN_TILE 1024
#define SCAN_NBLK ((N_NODES + SCAN_TILE - 1) / SCAN_TILE)   // 49
#define EW_EPT 8    // edges per octet per wave-iteration (8 independent chains)

__device__ __forceinline__ float sgpr_f(float x) {
    return __uint_as_float(__builtin_amdgcn_readfirstlane(__float_as_uint(x)));
}

#if defined(__has_builtin)
#if __has_builtin(__builtin_amdgcn_fdot2)
#define HAS_FDOT2 1
#endif
#endif

typedef _Float16 v2h_t __attribute__((ext_vector_type(2)));

__device__ __forceinline__ float fdot2f(__half2 a, __half2 b, float c) {
#ifdef HAS_FDOT2
    return __builtin_amdgcn_fdot2(*reinterpret_cast<v2h_t*>(&a),
                                  *reinterpret_cast<v2h_t*>(&b), c, false);
#else
    const float2 fa = __half22float2(a);
    const float2 fb = __half22float2(b);
    return fmaf(fa.x, fb.x, fmaf(fa.y, fb.y, c));
#endif
}

// packed relu: v_pk_max_f16 with inline constant 0
__device__ __forceinline__ __half2 relu_h2(__half2 x) {
    union { __half2 h; unsigned u; } a, r;
    a.h = x;
    asm("v_pk_max_f16 %0, %1, 0" : "=v"(r.u) : "v"(a.u));
    return r.h;
}

// DPP cross-lane moves (VALU pipe, no LDS).
// 0xB1 = quad_perm lane^1, 0x4E = quad_perm lane^2,
// 0x141 = ROW_HALF_MIRROR (lane i <-> 7-i within aligned 8-lane groups).
template <int CTRL>
__device__ __forceinline__ float dpp_mov_f32(float x) {
    return __int_as_float(__builtin_amdgcn_update_dpp(
        0, __float_as_int(x), CTRL, 0xF, 0xF, true));
}
template <int CTRL>
__device__ __forceinline__ int dpp_mov_i32(int x) {
    return __builtin_amdgcn_update_dpp(0, x, CTRL, 0xF, 0xF, true);
}
// full 8-lane (octet) all-reduce (validated r11)
__device__ __forceinline__ float oct_sum(float x) {
    x += dpp_mov_f32<0xB1>(x);
    x += dpp_mov_f32<0x4E>(x);
    x += dpp_mov_f32<0x141>(x);
    return x;
}

// ---------------------------------------------------------------------------
// Projection kernel, fp16-dot2 version (r16-proven): W staged in LDS as half2
// k-pairs (24 KB), inputs converted to half2, fdot2 with f32 accumulate.
// ---------------------------------------------------------------------------
__global__ __launch_bounds__(256) void proj_kernel(
    const float* __restrict__ qin, const float* __restrict__ kin, const float* __restrict__ vin,
    const float* __restrict__ Wq, const float* __restrict__ bq,
    const float* __restrict__ Wk, const float* __restrict__ bk,
    const float* __restrict__ Wv, const float* __restrict__ bv,
    __half* __restrict__ xq, __half* __restrict__ xk, __half* __restrict__ xv)
{
    // Wh[m][kp][c]: half2 {W[2kp][c], W[2kp+1][c]}, kp=0..31, c=0..63
    __shared__ unsigned Wh[3 * 2048];
    const int tid = threadIdx.x;
    #pragma unroll
    for (int it = 0; it < 8; ++it) {
        const int idx = it * 256 + tid;          // 0..2047
        const int kp = idx >> 6, c = idx & 63;
        {
            const __half2 h = __floats2half2_rn(Wq[(2 * kp) * 64 + c], Wq[(2 * kp + 1) * 64 + c]);
            Wh[idx] = *reinterpret_cast<const unsigned*>(&h);
        }
        {
            const __half2 h = __floats2half2_rn(Wk[(2 * kp) * 64 + c], Wk[(2 * kp + 1) * 64 + c]);
            Wh[2048 + idx] = *reinterpret_cast<const unsigned*>(&h);
        }
        {
            const __half2 h = __floats2half2_rn(Wv[(2 * kp) * 64 + c], Wv[(2 * kp + 1) * 64 + c]);
            Wh[4096 + idx] = *reinterpret_cast<const unsigned*>(&h);
        }
    }
    __syncthreads();

    const int cg = tid & 15;
    const int rg = tid >> 4;
    const int c0 = cg * 4;
    const int base = blockIdx.x * 64 + rg * 4;

    const float* ins[3]  = {qin, kin, vin};
    const float* bs[3]   = {bq, bk, bv};
    __half*      outs[3] = {xq, xk, xv};

    int rowi[4];
    #pragma unroll
    for (int rr = 0; rr < 4; ++rr)
        rowi[rr] = (base + rr < N_NODES) ? (base + rr) : (N_NODES - 1);

    #pragma unroll
    for (int m = 0; m < 3; ++m) {
        const float* in = ins[m];
        float4 acc[4];
        const float4 b4 = *reinterpret_cast<const float4*>(&bs[m][c0]);
        #pragma unroll
        for (int rr = 0; rr < 4; ++rr) acc[rr] = b4;

        for (int kk = 0; kk < 64; kk += 4) {
            __half2 xp[4][2];
            #pragma unroll
            for (int rr = 0; rr < 4; ++rr) {
                const float4 rv = *reinterpret_cast<const float4*>(&in[rowi[rr] * 64 + kk]);
                xp[rr][0] = __floats2half2_rn(rv.x, rv.y);
                xp[rr][1] = __floats2half2_rn(rv.z, rv.w);
            }
            #pragma unroll
            for (int h = 0; h < 2; ++h) {
                const int kp = (kk >> 1) + h;
                const uint4 wq = *reinterpret_cast<const uint4*>(&Wh[m * 2048 + kp * 64 + c0]);
                const __half2 w0 = *reinterpret_cast<const __half2*>(&wq.x);
                const __half2 w1 = *reinterpret_cast<const __half2*>(&wq.y);
                const __half2 w2 = *reinterpret_cast<const __half2*>(&wq.z);
                const __half2 w3 = *reinterpret_cast<const __half2*>(&wq.w);
                #pragma unroll
                for (int rr = 0; rr < 4; ++rr) {
                    acc[rr].x = fdot2f(xp[rr][h], w0, acc[rr].x);
                    acc[rr].y = fdot2f(xp[rr][h], w1, acc[rr].y);
                    acc[rr].z = fdot2f(xp[rr][h], w2, acc[rr].z);
                    acc[rr].w = fdot2f(xp[rr][h], w3, acc[rr].w);
                }
            }
        }
        #pragma unroll
        for (int rr = 0; rr < 4; ++rr) {
            if (base + rr < N_NODES) {
                union { __half2 h[2]; uint2 u; } pk;
                pk.h[0] = __floats2half2_rn(acc[rr].x, acc[rr].y);
                pk.h[1] = __floats2half2_rn(acc[rr].z, acc[rr].w);
                *reinterpret_cast<uint2*>(&outs[m][(size_t)(base + rr) * 64 + c0]) = pk.u;
            }
        }
    }
}

// ---------------------------------------------------------------------------
// p-precompute: pure streaming pass over edges (thread-per-edge, 64B/thread
// coalesced). pf[e] = edges[e].Wp + bp. Runs at HBM BW (~9us for 54MB).
// ---------------------------------------------------------------------------
__global__ __launch_bounds__(256) void p_kernel(
    const float* __restrict__ edges, const float* __restrict__ Wp,
    const float* __restrict__ bp, float* __restrict__ pf)
{
    const int e = blockIdx.x * 256 + threadIdx.x;
    float pr = bp[0];
    #pragma unroll
    for (int q4 = 0; q4 < 4; ++q4) {
        const float4 ev = *reinterpret_cast<const float4*>(&edges[(size_t)e * 16 + q4 * 4]);
        const float4 wv = *reinterpret_cast<const float4*>(&Wp[q4 * 4]);
        pr = fmaf(ev.x, wv.x, pr);
        pr = fmaf(ev.y, wv.y, pr);
        pr = fmaf(ev.z, wv.z, pr);
        pr = fmaf(ev.w, wv.w, pr);
    }
    pf[e] = pr;
}

// ---------------------------------------------------------------------------
// Hierarchical scan, step A: per-1024-element block sums (49 blocks).
// ---------------------------------------------------------------------------
__global__ __launch_bounds__(256) void scan_sums(
    const int* __restrict__ cnt, int* __restrict__ bsum)
{
    const int tid  = threadIdx.x;
    const int base = blockIdx.x * SCAN_TILE + tid * 4;
    int s = 0;
    if (base + 3 < N_NODES) {
        const int4 t = *reinterpret_cast<const int4*>(&cnt[base]);
        s = t.x + t.y + t.z + t.w;
    } else {
        #pragma unroll
        for (int i = 0; i < 4; ++i)
            if (base + i < N_NODES) s += cnt[base + i];
    }
    #pragma unroll
    for (int d = 1; d < 64; d <<= 1) s += __shfl_xor(s, d);
    __shared__ int ws[4];
    if ((tid & 63) == 0) ws[tid >> 6] = s;
    __syncthreads();
    if (tid == 0) bsum[blockIdx.x] = ws[0] + ws[1] + ws[2] + ws[3];
}

// ---------------------------------------------------------------------------
// Hierarchical scan, step B: exclusive scan of the 49 block sums (one wave).
// ---------------------------------------------------------------------------
__global__ __launch_bounds__(64) void scan_bsum(int* __restrict__ bsum)
{
    const int lane = threadIdx.x;
    const int v = (lane < SCAN_NBLK) ? bsum[lane] : 0;
    int incl = v;
    #pragma unroll
    for (int d = 1; d < 64; d <<= 1) {
        const int t = __shfl_up(incl, d);
        if (lane >= d) incl += t;
    }
    if (lane < SCAN_NBLK) bsum[lane] = incl - v;
}

// ---------------------------------------------------------------------------
// Hierarchical scan, step C: local exclusive scan + block offset.
// Writes off[] and re-purposes cnt[] (in-place) as the scatter cursor.
// ---------------------------------------------------------------------------
__global__ __launch_bounds__(256) void scan_final(
    int* __restrict__ cnt, const int* __restrict__ bsum, int* __restrict__ off)
{
    const int tid  = threadIdx.x;
    const int base = blockIdx.x * SCAN_TILE + tid * 4;

    int v0 = 0, v1 = 0, v2 = 0, v3 = 0;
    if (base + 3 < N_NODES) {
        const int4 t = *reinterpret_cast<const int4*>(&cnt[base]);
        v0 = t.x; v1 = t.y; v2 = t.z; v3 = t.w;
    } else {
        if (base + 0 < N_NODES) v0 = cnt[base + 0];
        if (base + 1 < N_NODES) v1 = cnt[base + 1];
        if (base + 2 < N_NODES) v2 = cnt[base + 2];
        if (base + 3 < N_NODES) v3 = cnt[base + 3];
    }
    const int s = v0 + v1 + v2 + v3;

    int incl = s;
    #pragma unroll
    for (int d = 1; d < 64; d <<= 1) {
        const int t = __shfl_up(incl, d);
        if ((tid & 63) >= d) incl += t;
    }
    __shared__ int wsum[4];
    const int wave = tid >> 6;
    if ((tid & 63) == 63) wsum[wave] = incl;
    __syncthreads();
    int woff = 0;
    #pragma unroll
    for (int w = 0; w < 3; ++w)
        if (w < wave) woff += wsum[w];

    int run = bsum[blockIdx.x] + woff + (incl - s);
    if (base + 0 < N_NODES) { off[base + 0] = run; cnt[base + 0] = run; run += v0; }
    if (base + 1 < N_NODES) { off[base + 1] = run; cnt[base + 1] = run; run += v1; }
    if (base + 2 < N_NODES) { off[base + 2] = run; cnt[base + 2] = run; run += v2; }
    if (base + 3 < N_NODES) { off[base + 3] = run; cnt[base + 3] = run; run += v3; }

    if (blockIdx.x == 0 && tid == 0) off[N_NODES] = E_EDGES;
}

// ---------------------------------------------------------------------------
// Edge-weights kernel: like r15/r17 but p is read precomputed from pf[e]
// (3.2MB stream, octet lanes share the cacheline) instead of re-deriving it
// from the 51.2MB edges array. Coalesced edge-order record + histogram.
// Record: word0 = src | (dst<<16); word1 = w[0..3] u8; word2 = w[4..7] u8;
//         word3 = p (f32). Softmax without max-subtraction.
// ---------------------------------------------------------------------------
__global__ __launch_bounds__(256) void edge_weights(
    const int* __restrict__ eidx, const float* __restrict__ pf,
    const float* __restrict__ W1, const float* __restrict__ b1,
    const float* __restrict__ W2, const float* __restrict__ b2,
    const __half* __restrict__ xq, const __half* __restrict__ xk,
    int* __restrict__ cnt, uint4* __restrict__ rece)
{
    const int tid  = threadIdx.x;
    const int lane = tid & 63;
    const int o    = lane >> 3;
    const int r    = lane & 7;
    const int wave = tid >> 6;

    __half2 W1h[4][8];
    #pragma unroll
    for (int i = 0; i < 4; ++i) {
        const float4 a0 = *reinterpret_cast<const float4*>(&W1[(8 * r + 2 * i) * 8]);
        const float4 a1 = *reinterpret_cast<const float4*>(&W1[(8 * r + 2 * i) * 8 + 4]);
        const float4 c0 = *reinterpret_cast<const float4*>(&W1[(8 * r + 2 * i + 1) * 8]);
        const float4 c1 = *reinterpret_cast<const float4*>(&W1[(8 * r + 2 * i + 1) * 8 + 4]);
        W1h[i][0] = __floats2half2_rn(a0.x, c0.x);
        W1h[i][1] = __floats2half2_rn(a0.y, c0.y);
        W1h[i][2] = __floats2half2_rn(a0.z, c0.z);
        W1h[i][3] = __floats2half2_rn(a0.w, c0.w);
        W1h[i][4] = __floats2half2_rn(a1.x, c1.x);
        W1h[i][5] = __floats2half2_rn(a1.y, c1.y);
        W1h[i][6] = __floats2half2_rn(a1.z, c1.z);
        W1h[i][7] = __floats2half2_rn(a1.w, c1.w);
    }
    float W2col[8];
    #pragma unroll
    for (int jj = 0; jj < 8; ++jj) W2col[jj] = W2[jj * 8 + r];
    float b1u[8];
    #pragma unroll
    for (int j = 0; j < 8; ++j) b1u[j] = sgpr_f(b1[j]);
    const float b2r = b2[r];

    const int wb = (blockIdx.x * 4 + wave) * (8 * EW_EPT);

    #pragma unroll
    for (int t = 0; t < EW_EPT; ++t) {
        const int e = wb + t * 8 + o;

        const int2 sd = *reinterpret_cast<const int2*>(&eidx[2 * e]);
        const float p = pf[e];

        uint4 q4u = *reinterpret_cast<const uint4*>(&xq[(size_t)sd.x * 64 + 8 * r]);
        uint4 k4u = *reinterpret_cast<const uint4*>(&xk[(size_t)sd.y * 64 + 8 * r]);

        const __half2 p2 = __float2half2_rn(p);
        const __half2* qh = reinterpret_cast<const __half2*>(&q4u);
        const __half2* kh = reinterpret_cast<const __half2*>(&k4u);

        float part[8];
        #pragma unroll
        for (int jj = 0; jj < 8; ++jj) part[jj] = 0.f;
        #pragma unroll
        for (int i = 0; i < 4; ++i) {
            const __half2 d = relu_h2(__hadd2(__hsub2(kh[i], qh[i]), p2));
            #pragma unroll
            for (int jj = 0; jj < 8; ++jj)
                part[jj] = fdot2f(d, W1h[i][jj], part[jj]);
        }
        #pragma unroll
        for (int jj = 0; jj < 8; ++jj) part[jj] = oct_sum(part[jj]);

        float h2 = b2r;
        #pragma unroll
        for (int jj = 0; jj < 8; ++jj) {
            const float h1 = fmaxf(part[jj] + b1u[jj], 0.f);
            h2 = fmaf(h1, W2col[jj], h2);
        }

        // softmax without max-subtraction (|h2| << 88, f32-exp safe)
        const float ex = __expf(h2);
        const float sm = oct_sum(ex);
        const float w  = ex / sm;

        // quantize to u8 (*255, deferred 1/255 in node_accum's epilogue)
        const unsigned wu = (unsigned)__float2uint_rn(w * 255.f);
        unsigned word = wu << (8 * (r & 3));
        word |= (unsigned)dpp_mov_i32<0xB1>((int)word);   // quad or-combine
        word |= (unsigned)dpp_mov_i32<0x4E>((int)word);
        const unsigned other = (unsigned)dpp_mov_i32<0x141>((int)word); // other quad's word

        if (r == 0) {
            uint4 rec;
            rec.x = (unsigned)sd.x | ((unsigned)sd.y << 16);
            rec.y = word;    // w[0..3]
            rec.z = other;   // w[4..7]
            rec.w = __float_as_uint(p);
            rece[e] = rec;   // coalesced: 8 octets -> 128B contiguous
        }
        if (r == 1) atomicAdd(&cnt[sd.x], 1);
    }
}

// ---------------------------------------------------------------------------
// Scatter: ONE random 16B store per edge. src comes from the record.
// ---------------------------------------------------------------------------
__global__ __launch_bounds__(256) void scatter_kernel(
    const uint4* __restrict__ rece, int* __restrict__ cursor,
    uint4* __restrict__ reccsr)
{
    const int e = blockIdx.x * 256 + threadIdx.x;
    const uint4 rec = rece[e];
    const int src = (int)(rec.x & 0xFFFFu);
    const int pos = atomicAdd(&cursor[src], 1);
    reccsr[pos] = rec;
}

// ---------------------------------------------------------------------------
// Node accumulation (r14-proven): 16 lanes per node (2 sub-octets, alternate
// edges). Lane r owns channels 8r..8r+7; weights u8 with deferred 1/255.
// ---------------------------------------------------------------------------
__global__ __launch_bounds__(256) void node_accum(
    const int* __restrict__ off, const uint4* __restrict__ reccsr,
    const __half* __restrict__ xv, float* __restrict__ out)
{
    const int tid  = threadIdx.x;
    const int lane = tid & 63;
    const int grp  = lane >> 4;
    const int sub  = (lane >> 3) & 1;
    const int r    = lane & 7;
    const int wave = tid >> 6;

    const int node = blockIdx.x * 16 + wave * 4 + grp;

    const int beg = off[node];
    const int end = off[node + 1];

    float acc[8];
    #pragma unroll
    for (int i = 0; i < 8; ++i) acc[i] = 0.f;

    int j = beg + sub;
    uint4 rec;
    if (j < end) rec = reccsr[j];

    for (; j < end; j += 2) {
        const uint4 cur = rec;
        const int   dst = (int)(cur.x >> 16);
        const float p   = __uint_as_float(cur.w);

        union { uint4 u; __half2 h[4]; } v4;
        v4.u = *reinterpret_cast<const uint4*>(&xv[(size_t)dst * 64 + 8 * r]);

        if (j + 2 < end) rec = reccsr[j + 2];

        float wf[8];
        #pragma unroll
        for (int i = 0; i < 4; ++i) {
            wf[i]     = (float)((cur.y >> (8 * i)) & 255u);
            wf[4 + i] = (float)((cur.z >> (8 * i)) & 255u);
        }

        #pragma unroll
        for (int i = 0; i < 4; ++i) {
            const float2 fv = __half22float2(v4.h[i]);
            acc[2 * i]     = fmaf(fv.x + p, wf[2 * i],     acc[2 * i]);
            acc[2 * i + 1] = fmaf(fv.y + p, wf[2 * i + 1], acc[2 * i + 1]);
        }
    }

    #pragma unroll
    for (int i = 0; i < 8; ++i)
        acc[i] += __shfl_xor(acc[i], 8);

    if (sub == 0) {
        const float c = 1.f / 255.f;
        float* orow = &out[(size_t)node * 64 + 8 * r];
        *reinterpret_cast<float4*>(orow) =
            make_float4(acc[0] * c, acc[1] * c, acc[2] * c, acc[3] * c);
        *reinterpret_cast<float4*>(orow + 4) =
            make_float4(acc[4] * c, acc[5] * c, acc[6] * c, acc[7] * c);
    }
}

extern "C" void kernel_launch(void* const* d_in, const int* in_sizes, int n_in,
                              void* d_out, int out_size, void* d_ws, size_t ws_size,
                              hipStream_t stream) {
    const float* q     = (const float*)d_in[0];
    const float* k     = (const float*)d_in[1];
    const float* v     = (const float*)d_in[2];
    const float* edges = (const float*)d_in[3];
    const int*   eidx  = (const int*)d_in[4];
    const float* Wq    = (const float*)d_in[5];
    const float* bq    = (const float*)d_in[6];
    const float* Wk    = (const float*)d_in[7];
    const float* bk    = (const float*)d_in[8];
    const float* Wv    = (const float*)d_in[9];
    const float* bv    = (const float*)d_in[10];
    const float* Wp    = (const float*)d_in[11];
    const float* bp    = (const float*)d_in[12];
    const float* W1    = (const float*)d_in[13];
    const float* b1    = (const float*)d_in[14];
    const float* W2    = (const float*)d_in[15];
    const float* b2    = (const float*)d_in[16];
    float* out = (float*)d_out;

    // workspace layout
    char* ws = (char*)d_ws;
    __half* xq = (__half*)ws;          ws += (size_t)N_NODES * 64 * sizeof(__half);
    __half* xk = (__half*)ws;          ws += (size_t)N_NODES * 64 * sizeof(__half);
    __half* xv = (__half*)ws;          ws += (size_t)N_NODES * 64 * sizeof(__half);
    int* cnt  = (int*)ws;              ws += (size_t)(N_NODES + 64) * sizeof(int);
    int* off  = (int*)ws;              ws += (size_t)(N_NODES + 64) * sizeof(int);
    int* bsum = (int*)ws;              ws += (size_t)64 * sizeof(int);
    float* pf = (float*)ws;            ws += (size_t)E_EDGES * sizeof(float);   // 3.2 MB
    uint4* rece   = (uint4*)ws;        ws += (size_t)E_EDGES * sizeof(uint4);   // 12.8 MB
    uint4* reccsr = (uint4*)ws;        ws += (size_t)E_EDGES * sizeof(uint4);   // 12.8 MB

    hipMemsetAsync(cnt, 0, (size_t)N_NODES * sizeof(int), stream);

    p_kernel<<<dim3(E_EDGES / 256), dim3(256), 0, stream>>>(edges, Wp, bp, pf);

    proj_kernel<<<dim3((N_NODES + 63) / 64), dim3(256), 0, stream>>>(
        q, k, v, Wq, bq, Wk, bk, Wv, bv, xq, xk, xv);

    edge_weights<<<dim3(E_EDGES / (32 * EW_EPT)), dim3(256), 0, stream>>>(
        eidx, pf, W1, b1, W2, b2, xq, xk, cnt, rece);

    scan_sums<<<dim3(SCAN_NBLK), dim3(256), 0, stream>>>(cnt, bsum);
    scan_bsum<<<dim3(1), dim3(64), 0, stream>>>(bsum);
    scan_final<<<dim3(SCAN_NBLK), dim3(256), 0, stream>>>(cnt, bsum, off);

    scatter_kernel<<<dim3(E_EDGES / 256), dim3(256), 0, stream>>>(
        rece, cnt, reccsr);

    node_accum<<<dim3(N_NODES / 16), dim3(256), 0, stream>>>(
        off, reccsr, xv, out);
}

// Round 20
// 162.256 us; speedup vs baseline: 1.1029x; 1.1029x over previous
//
#include <hip/hip_runtime.h>
#include <hip/hip_fp16.h>

#define N_NODES 50000
#define E_EDGES 800000
#define SCAN_TILE 1024
#define SCAN_NBLK ((N_NODES + SCAN_TILE - 1) / SCAN_TILE)   // 49
#define EW_EPT 10   // edges/octet/iter: 320 edges per block -> 2500 blocks EXACT

__device__ __forceinline__ float sgpr_f(float x) {
    return __uint_as_float(__builtin_amdgcn_readfirstlane(__float_as_uint(x)));
}

#if defined(__has_builtin)
#if __has_builtin(__builtin_amdgcn_fdot2)
#define HAS_FDOT2 1
#endif
#endif

typedef _Float16 v2h_t __attribute__((ext_vector_type(2)));

__device__ __forceinline__ float fdot2f(__half2 a, __half2 b, float c) {
#ifdef HAS_FDOT2
    return __builtin_amdgcn_fdot2(*reinterpret_cast<v2h_t*>(&a),
                                  *reinterpret_cast<v2h_t*>(&b), c, false);
#else
    const float2 fa = __half22float2(a);
    const float2 fb = __half22float2(b);
    return fmaf(fa.x, fb.x, fmaf(fa.y, fb.y, c));
#endif
}

// packed relu: v_pk_max_f16 with inline constant 0
__device__ __forceinline__ __half2 relu_h2(__half2 x) {
    union { __half2 h; unsigned u; } a, r;
    a.h = x;
    asm("v_pk_max_f16 %0, %1, 0" : "=v"(r.u) : "v"(a.u));
    return r.h;
}

// DPP cross-lane moves (VALU pipe, no LDS).
// 0xB1 = quad_perm lane^1, 0x4E = quad_perm lane^2,
// 0x141 = ROW_HALF_MIRROR (lane i <-> 7-i within aligned 8-lane groups).
template <int CTRL>
__device__ __forceinline__ float dpp_mov_f32(float x) {
    return __int_as_float(__builtin_amdgcn_update_dpp(
        0, __float_as_int(x), CTRL, 0xF, 0xF, true));
}
template <int CTRL>
__device__ __forceinline__ int dpp_mov_i32(int x) {
    return __builtin_amdgcn_update_dpp(0, x, CTRL, 0xF, 0xF, true);
}
// full 8-lane (octet) all-reduce (validated r11)
__device__ __forceinline__ float oct_sum(float x) {
    x += dpp_mov_f32<0xB1>(x);
    x += dpp_mov_f32<0x4E>(x);
    x += dpp_mov_f32<0x141>(x);
    return x;
}

// ---------------------------------------------------------------------------
// Projection kernel, fp16-dot2 version (r16-proven): W staged in LDS as half2
// k-pairs (24 KB), inputs converted to half2, fdot2 with f32 accumulate.
// ---------------------------------------------------------------------------
__global__ __launch_bounds__(256) void proj_kernel(
    const float* __restrict__ qin, const float* __restrict__ kin, const float* __restrict__ vin,
    const float* __restrict__ Wq, const float* __restrict__ bq,
    const float* __restrict__ Wk, const float* __restrict__ bk,
    const float* __restrict__ Wv, const float* __restrict__ bv,
    __half* __restrict__ xq, __half* __restrict__ xk, __half* __restrict__ xv)
{
    // Wh[m][kp][c]: half2 {W[2kp][c], W[2kp+1][c]}, kp=0..31, c=0..63
    __shared__ unsigned Wh[3 * 2048];
    const int tid = threadIdx.x;
    #pragma unroll
    for (int it = 0; it < 8; ++it) {
        const int idx = it * 256 + tid;          // 0..2047
        const int kp = idx >> 6, c = idx & 63;
        {
            const __half2 h = __floats2half2_rn(Wq[(2 * kp) * 64 + c], Wq[(2 * kp + 1) * 64 + c]);
            Wh[idx] = *reinterpret_cast<const unsigned*>(&h);
        }
        {
            const __half2 h = __floats2half2_rn(Wk[(2 * kp) * 64 + c], Wk[(2 * kp + 1) * 64 + c]);
            Wh[2048 + idx] = *reinterpret_cast<const unsigned*>(&h);
        }
        {
            const __half2 h = __floats2half2_rn(Wv[(2 * kp) * 64 + c], Wv[(2 * kp + 1) * 64 + c]);
            Wh[4096 + idx] = *reinterpret_cast<const unsigned*>(&h);
        }
    }
    __syncthreads();

    const int cg = tid & 15;
    const int rg = tid >> 4;
    const int c0 = cg * 4;
    const int base = blockIdx.x * 64 + rg * 4;

    const float* ins[3]  = {qin, kin, vin};
    const float* bs[3]   = {bq, bk, bv};
    __half*      outs[3] = {xq, xk, xv};

    int rowi[4];
    #pragma unroll
    for (int rr = 0; rr < 4; ++rr)
        rowi[rr] = (base + rr < N_NODES) ? (base + rr) : (N_NODES - 1);

    #pragma unroll
    for (int m = 0; m < 3; ++m) {
        const float* in = ins[m];
        float4 acc[4];
        const float4 b4 = *reinterpret_cast<const float4*>(&bs[m][c0]);
        #pragma unroll
        for (int rr = 0; rr < 4; ++rr) acc[rr] = b4;

        for (int kk = 0; kk < 64; kk += 4) {
            __half2 xp[4][2];
            #pragma unroll
            for (int rr = 0; rr < 4; ++rr) {
                const float4 rv = *reinterpret_cast<const float4*>(&in[rowi[rr] * 64 + kk]);
                xp[rr][0] = __floats2half2_rn(rv.x, rv.y);
                xp[rr][1] = __floats2half2_rn(rv.z, rv.w);
            }
            #pragma unroll
            for (int h = 0; h < 2; ++h) {
                const int kp = (kk >> 1) + h;
                const uint4 wq = *reinterpret_cast<const uint4*>(&Wh[m * 2048 + kp * 64 + c0]);
                const __half2 w0 = *reinterpret_cast<const __half2*>(&wq.x);
                const __half2 w1 = *reinterpret_cast<const __half2*>(&wq.y);
                const __half2 w2 = *reinterpret_cast<const __half2*>(&wq.z);
                const __half2 w3 = *reinterpret_cast<const __half2*>(&wq.w);
                #pragma unroll
                for (int rr = 0; rr < 4; ++rr) {
                    acc[rr].x = fdot2f(xp[rr][h], w0, acc[rr].x);
                    acc[rr].y = fdot2f(xp[rr][h], w1, acc[rr].y);
                    acc[rr].z = fdot2f(xp[rr][h], w2, acc[rr].z);
                    acc[rr].w = fdot2f(xp[rr][h], w3, acc[rr].w);
                }
            }
        }
        #pragma unroll
        for (int rr = 0; rr < 4; ++rr) {
            if (base + rr < N_NODES) {
                union { __half2 h[2]; uint2 u; } pk;
                pk.h[0] = __floats2half2_rn(acc[rr].x, acc[rr].y);
                pk.h[1] = __floats2half2_rn(acc[rr].z, acc[rr].w);
                *reinterpret_cast<uint2*>(&outs[m][(size_t)(base + rr) * 64 + c0]) = pk.u;
            }
        }
    }
}

// ---------------------------------------------------------------------------
// Hierarchical scan, step A: per-1024-element block sums (49 blocks).
// ---------------------------------------------------------------------------
__global__ __launch_bounds__(256) void scan_sums(
    const int* __restrict__ cnt, int* __restrict__ bsum)
{
    const int tid  = threadIdx.x;
    const int base = blockIdx.x * SCAN_TILE + tid * 4;
    int s = 0;
    if (base + 3 < N_NODES) {
        const int4 t = *reinterpret_cast<const int4*>(&cnt[base]);
        s = t.x + t.y + t.z + t.w;
    } else {
        #pragma unroll
        for (int i = 0; i < 4; ++i)
            if (base + i < N_NODES) s += cnt[base + i];
    }
    #pragma unroll
    for (int d = 1; d < 64; d <<= 1) s += __shfl_xor(s, d);
    __shared__ int ws[4];
    if ((tid & 63) == 0) ws[tid >> 6] = s;
    __syncthreads();
    if (tid == 0) bsum[blockIdx.x] = ws[0] + ws[1] + ws[2] + ws[3];
}

// ---------------------------------------------------------------------------
// Hierarchical scan, step B: exclusive scan of the 49 block sums (one wave).
// ---------------------------------------------------------------------------
__global__ __launch_bounds__(64) void scan_bsum(int* __restrict__ bsum)
{
    const int lane = threadIdx.x;
    const int v = (lane < SCAN_NBLK) ? bsum[lane] : 0;
    int incl = v;
    #pragma unroll
    for (int d = 1; d < 64; d <<= 1) {
        const int t = __shfl_up(incl, d);
        if (lane >= d) incl += t;
    }
    if (lane < SCAN_NBLK) bsum[lane] = incl - v;
}

// ---------------------------------------------------------------------------
// Hierarchical scan, step C: local exclusive scan + block offset.
// Writes off[] and re-purposes cnt[] (in-place) as the scatter cursor.
// ---------------------------------------------------------------------------
__global__ __launch_bounds__(256) void scan_final(
    int* __restrict__ cnt, const int* __restrict__ bsum, int* __restrict__ off)
{
    const int tid  = threadIdx.x;
    const int base = blockIdx.x * SCAN_TILE + tid * 4;

    int v0 = 0, v1 = 0, v2 = 0, v3 = 0;
    if (base + 3 < N_NODES) {
        const int4 t = *reinterpret_cast<const int4*>(&cnt[base]);
        v0 = t.x; v1 = t.y; v2 = t.z; v3 = t.w;
    } else {
        if (base + 0 < N_NODES) v0 = cnt[base + 0];
        if (base + 1 < N_NODES) v1 = cnt[base + 1];
        if (base + 2 < N_NODES) v2 = cnt[base + 2];
        if (base + 3 < N_NODES) v3 = cnt[base + 3];
    }
    const int s = v0 + v1 + v2 + v3;

    int incl = s;
    #pragma unroll
    for (int d = 1; d < 64; d <<= 1) {
        const int t = __shfl_up(incl, d);
        if ((tid & 63) >= d) incl += t;
    }
    __shared__ int wsum[4];
    const int wave = tid >> 6;
    if ((tid & 63) == 63) wsum[wave] = incl;
    __syncthreads();
    int woff = 0;
    #pragma unroll
    for (int w = 0; w < 3; ++w)
        if (w < wave) woff += wsum[w];

    int run = bsum[blockIdx.x] + woff + (incl - s);
    if (base + 0 < N_NODES) { off[base + 0] = run; cnt[base + 0] = run; run += v0; }
    if (base + 1 < N_NODES) { off[base + 1] = run; cnt[base + 1] = run; run += v1; }
    if (base + 2 < N_NODES) { off[base + 2] = run; cnt[base + 2] = run; run += v2; }
    if (base + 3 < N_NODES) { off[base + 3] = run; cnt[base + 3] = run; run += v3; }

    if (blockIdx.x == 0 && tid == 0) off[N_NODES] = E_EDGES;
}

// ---------------------------------------------------------------------------
// Edge-weights kernel (r17-proven math, EW_EPT=10, grid 2500 EXACT):
// coalesced edge-order record + histogram. p computed in-kernel from edges.
// Record: word0 = src | (dst<<16); word1 = w[0..3] u8; word2 = w[4..7] u8;
//         word3 = p (f32). Softmax without max-subtraction.
// ---------------------------------------------------------------------------
__global__ __launch_bounds__(256) void edge_weights(
    const int* __restrict__ eidx, const float* __restrict__ edges,
    const float* __restrict__ Wp, const float* __restrict__ bp,
    const float* __restrict__ W1, const float* __restrict__ b1,
    const float* __restrict__ W2, const float* __restrict__ b2,
    const __half* __restrict__ xq, const __half* __restrict__ xk,
    int* __restrict__ cnt, uint4* __restrict__ rece)
{
    const int tid  = threadIdx.x;
    const int lane = tid & 63;
    const int o    = lane >> 3;
    const int r    = lane & 7;
    const int wave = tid >> 6;

    __half2 W1h[4][8];
    #pragma unroll
    for (int i = 0; i < 4; ++i) {
        const float4 a0 = *reinterpret_cast<const float4*>(&W1[(8 * r + 2 * i) * 8]);
        const float4 a1 = *reinterpret_cast<const float4*>(&W1[(8 * r + 2 * i) * 8 + 4]);
        const float4 c0 = *reinterpret_cast<const float4*>(&W1[(8 * r + 2 * i + 1) * 8]);
        const float4 c1 = *reinterpret_cast<const float4*>(&W1[(8 * r + 2 * i + 1) * 8 + 4]);
        W1h[i][0] = __floats2half2_rn(a0.x, c0.x);
        W1h[i][1] = __floats2half2_rn(a0.y, c0.y);
        W1h[i][2] = __floats2half2_rn(a0.z, c0.z);
        W1h[i][3] = __floats2half2_rn(a0.w, c0.w);
        W1h[i][4] = __floats2half2_rn(a1.x, c1.x);
        W1h[i][5] = __floats2half2_rn(a1.y, c1.y);
        W1h[i][6] = __floats2half2_rn(a1.z, c1.z);
        W1h[i][7] = __floats2half2_rn(a1.w, c1.w);
    }
    float W2col[8];
    #pragma unroll
    for (int jj = 0; jj < 8; ++jj) W2col[jj] = W2[jj * 8 + r];
    float b1u[8];
    #pragma unroll
    for (int j = 0; j < 8; ++j) b1u[j] = sgpr_f(b1[j]);
    const float b2r = b2[r];
    const float wpA = Wp[2 * r], wpB = Wp[2 * r + 1];
    const float bp0 = sgpr_f(bp[0]);

    const int wb = (blockIdx.x * 4 + wave) * (8 * EW_EPT);

    #pragma unroll
    for (int t = 0; t < EW_EPT; ++t) {
        const int e = wb + t * 8 + o;

        const int2 sd = *reinterpret_cast<const int2*>(&eidx[2 * e]);
        const float2 e2 = *reinterpret_cast<const float2*>(&edges[(size_t)e * 16 + 2 * r]);

        uint4 q4u = *reinterpret_cast<const uint4*>(&xq[(size_t)sd.x * 64 + 8 * r]);
        uint4 k4u = *reinterpret_cast<const uint4*>(&xk[(size_t)sd.y * 64 + 8 * r]);

        float p = fmaf(e2.x, wpA, e2.y * wpB);
        p = oct_sum(p) + bp0;

        const __half2 p2 = __float2half2_rn(p);
        const __half2* qh = reinterpret_cast<const __half2*>(&q4u);
        const __half2* kh = reinterpret_cast<const __half2*>(&k4u);

        float part[8];
        #pragma unroll
        for (int jj = 0; jj < 8; ++jj) part[jj] = 0.f;
        #pragma unroll
        for (int i = 0; i < 4; ++i) {
            const __half2 d = relu_h2(__hadd2(__hsub2(kh[i], qh[i]), p2));
            #pragma unroll
            for (int jj = 0; jj < 8; ++jj)
                part[jj] = fdot2f(d, W1h[i][jj], part[jj]);
        }
        #pragma unroll
        for (int jj = 0; jj < 8; ++jj) part[jj] = oct_sum(part[jj]);

        float h2 = b2r;
        #pragma unroll
        for (int jj = 0; jj < 8; ++jj) {
            const float h1 = fmaxf(part[jj] + b1u[jj], 0.f);
            h2 = fmaf(h1, W2col[jj], h2);
        }

        // softmax without max-subtraction (|h2| << 88, f32-exp safe)
        const float ex = __expf(h2);
        const float sm = oct_sum(ex);
        const float w  = ex / sm;

        // quantize to u8 (*255, deferred 1/255 in node_accum's epilogue)
        const unsigned wu = (unsigned)__float2uint_rn(w * 255.f);
        unsigned word = wu << (8 * (r & 3));
        word |= (unsigned)dpp_mov_i32<0xB1>((int)word);   // quad or-combine
        word |= (unsigned)dpp_mov_i32<0x4E>((int)word);
        const unsigned other = (unsigned)dpp_mov_i32<0x141>((int)word); // other quad's word

        if (r == 0) {
            uint4 rec;
            rec.x = (unsigned)sd.x | ((unsigned)sd.y << 16);
            rec.y = word;    // w[0..3]
            rec.z = other;   // w[4..7]
            rec.w = __float_as_uint(p);
            rece[e] = rec;   // coalesced: 8 octets -> 128B contiguous
        }
        if (r == 1) atomicAdd(&cnt[sd.x], 1);
    }
}

// ---------------------------------------------------------------------------
// Scatter: ONE random 16B store per edge. src comes from the record.
// ---------------------------------------------------------------------------
__global__ __launch_bounds__(256) void scatter_kernel(
    const uint4* __restrict__ rece, int* __restrict__ cursor,
    uint4* __restrict__ reccsr)
{
    const int e = blockIdx.x * 256 + threadIdx.x;
    const uint4 rec = rece[e];
    const int src = (int)(rec.x & 0xFFFFu);
    const int pos = atomicAdd(&cursor[src], 1);
    reccsr[pos] = rec;
}

// ---------------------------------------------------------------------------
// Node accumulation (r14-proven): 16 lanes per node (2 sub-octets, alternate
// edges). Lane r owns channels 8r..8r+7; weights u8 with deferred 1/255.
// ---------------------------------------------------------------------------
__global__ __launch_bounds__(256) void node_accum(
    const int* __restrict__ off, const uint4* __restrict__ reccsr,
    const __half* __restrict__ xv, float* __restrict__ out)
{
    const int tid  = threadIdx.x;
    const int lane = tid & 63;
    const int grp  = lane >> 4;
    const int sub  = (lane >> 3) & 1;
    const int r    = lane & 7;
    const int wave = tid >> 6;

    const int node = blockIdx.x * 16 + wave * 4 + grp;

    const int beg = off[node];
    const int end = off[node + 1];

    float acc[8];
    #pragma unroll
    for (int i = 0; i < 8; ++i) acc[i] = 0.f;

    int j = beg + sub;
    uint4 rec;
    if (j < end) rec = reccsr[j];

    for (; j < end; j += 2) {
        const uint4 cur = rec;
        const int   dst = (int)(cur.x >> 16);
        const float p   = __uint_as_float(cur.w);

        union { uint4 u; __half2 h[4]; } v4;
        v4.u = *reinterpret_cast<const uint4*>(&xv[(size_t)dst * 64 + 8 * r]);

        if (j + 2 < end) rec = reccsr[j + 2];

        float wf[8];
        #pragma unroll
        for (int i = 0; i < 4; ++i) {
            wf[i]     = (float)((cur.y >> (8 * i)) & 255u);
            wf[4 + i] = (float)((cur.z >> (8 * i)) & 255u);
        }

        #pragma unroll
        for (int i = 0; i < 4; ++i) {
            const float2 fv = __half22float2(v4.h[i]);
            acc[2 * i]     = fmaf(fv.x + p, wf[2 * i],     acc[2 * i]);
            acc[2 * i + 1] = fmaf(fv.y + p, wf[2 * i + 1], acc[2 * i + 1]);
        }
    }

    #pragma unroll
    for (int i = 0; i < 8; ++i)
        acc[i] += __shfl_xor(acc[i], 8);

    if (sub == 0) {
        const float c = 1.f / 255.f;
        float* orow = &out[(size_t)node * 64 + 8 * r];
        *reinterpret_cast<float4*>(orow) =
            make_float4(acc[0] * c, acc[1] * c, acc[2] * c, acc[3] * c);
        *reinterpret_cast<float4*>(orow + 4) =
            make_float4(acc[4] * c, acc[5] * c, acc[6] * c, acc[7] * c);
    }
}

extern "C" void kernel_launch(void* const* d_in, const int* in_sizes, int n_in,
                              void* d_out, int out_size, void* d_ws, size_t ws_size,
                              hipStream_t stream) {
    const float* q     = (const float*)d_in[0];
    const float* k     = (const float*)d_in[1];
    const float* v     = (const float*)d_in[2];
    const float* edges = (const float*)d_in[3];
    const int*   eidx  = (const int*)d_in[4];
    const float* Wq    = (const float*)d_in[5];
    const float* bq    = (const float*)d_in[6];
    const float* Wk    = (const float*)d_in[7];
    const float* bk    = (const float*)d_in[8];
    const float* Wv    = (const float*)d_in[9];
    const float* bv    = (const float*)d_in[10];
    const float* Wp    = (const float*)d_in[11];
    const float* bp    = (const float*)d_in[12];
    const float* W1    = (const float*)d_in[13];
    const float* b1    = (const float*)d_in[14];
    const float* W2    = (const float*)d_in[15];
    const float* b2    = (const float*)d_in[16];
    float* out = (float*)d_out;

    // workspace layout
    char* ws = (char*)d_ws;
    __half* xq = (__half*)ws;          ws += (size_t)N_NODES * 64 * sizeof(__half);
    __half* xk = (__half*)ws;          ws += (size_t)N_NODES * 64 * sizeof(__half);
    __half* xv = (__half*)ws;          ws += (size_t)N_NODES * 64 * sizeof(__half);
    int* cnt  = (int*)ws;              ws += (size_t)(N_NODES + 64) * sizeof(int);
    int* off  = (int*)ws;              ws += (size_t)(N_NODES + 64) * sizeof(int);
    int* bsum = (int*)ws;              ws += (size_t)64 * sizeof(int);
    uint4* rece   = (uint4*)ws;        ws += (size_t)E_EDGES * sizeof(uint4);   // 12.8 MB
    uint4* reccsr = (uint4*)ws;        ws += (size_t)E_EDGES * sizeof(uint4);   // 12.8 MB

    hipMemsetAsync(cnt, 0, (size_t)N_NODES * sizeof(int), stream);

    proj_kernel<<<dim3((N_NODES + 63) / 64), dim3(256), 0, stream>>>(
        q, k, v, Wq, bq, Wk, bk, Wv, bv, xq, xk, xv);

    edge_weights<<<dim3(E_EDGES / (32 * EW_EPT)), dim3(256), 0, stream>>>(
        eidx, edges, Wp, bp, W1, b1, W2, b2, xq, xk, cnt, rece);

    scan_sums<<<dim3(SCAN_NBLK), dim3(256), 0, stream>>>(cnt, bsum);
    scan_bsum<<<dim3(1), dim3(64), 0, stream>>>(bsum);
    scan_final<<<dim3(SCAN_NBLK), dim3(256), 0, stream>>>(cnt, bsum, off);

    scatter_kernel<<<dim3(E_EDGES / 256), dim3(256), 0, stream>>>(
        rece, cnt, reccsr);

    node_accum<<<dim3(N_NODES / 16), dim3(256), 0, stream>>>(
        off, reccsr, xv, out);
}

// Round 21
// 153.115 us; speedup vs baseline: 1.1687x; 1.0597x over previous
//
#include <hip/hip_runtime.h>
#include <hip/hip_fp16.h>

#define N_NODES 50000
#define E_EDGES 800000
#define SCAN_TILE 1024
#define SCAN_NBLK ((N_NODES + SCAN_TILE - 1) / SCAN_TILE)   // 49
#define EW_EPT 20   // edges/octet/iter: 640 edges per block -> 1250 blocks EXACT

__device__ __forceinline__ float sgpr_f(float x) {
    return __uint_as_float(__builtin_amdgcn_readfirstlane(__float_as_uint(x)));
}

#if defined(__has_builtin)
#if __has_builtin(__builtin_amdgcn_fdot2)
#define HAS_FDOT2 1
#endif
#endif

typedef _Float16 v2h_t __attribute__((ext_vector_type(2)));

__device__ __forceinline__ float fdot2f(__half2 a, __half2 b, float c) {
#ifdef HAS_FDOT2
    return __builtin_amdgcn_fdot2(*reinterpret_cast<v2h_t*>(&a),
                                  *reinterpret_cast<v2h_t*>(&b), c, false);
#else
    const float2 fa = __half22float2(a);
    const float2 fb = __half22float2(b);
    return fmaf(fa.x, fb.x, fmaf(fa.y, fb.y, c));
#endif
}

// packed relu: v_pk_max_f16 with inline constant 0
__device__ __forceinline__ __half2 relu_h2(__half2 x) {
    union { __half2 h; unsigned u; } a, r;
    a.h = x;
    asm("v_pk_max_f16 %0, %1, 0" : "=v"(r.u) : "v"(a.u));
    return r.h;
}

// DPP cross-lane moves (VALU pipe, no LDS).
// 0xB1 = quad_perm lane^1, 0x4E = quad_perm lane^2,
// 0x141 = ROW_HALF_MIRROR (lane i <-> 7-i within aligned 8-lane groups).
template <int CTRL>
__device__ __forceinline__ float dpp_mov_f32(float x) {
    return __int_as_float(__builtin_amdgcn_update_dpp(
        0, __float_as_int(x), CTRL, 0xF, 0xF, true));
}
template <int CTRL>
__device__ __forceinline__ int dpp_mov_i32(int x) {
    return __builtin_amdgcn_update_dpp(0, x, CTRL, 0xF, 0xF, true);
}
// full 8-lane (octet) all-reduce (validated r11)
__device__ __forceinline__ float oct_sum(float x) {
    x += dpp_mov_f32<0xB1>(x);
    x += dpp_mov_f32<0x4E>(x);
    x += dpp_mov_f32<0x141>(x);
    return x;
}

// ---------------------------------------------------------------------------
// Projection kernel, fp16-dot2 version (r16-proven): W staged in LDS as half2
// k-pairs (24 KB), inputs converted to half2, fdot2 with f32 accumulate.
// Also zeroes cnt[] (replaces the memset dispatch; completes before
// edge_weights' histogram atomics by stream order).
// ---------------------------------------------------------------------------
__global__ __launch_bounds__(256) void proj_kernel(
    const float* __restrict__ qin, const float* __restrict__ kin, const float* __restrict__ vin,
    const float* __restrict__ Wq, const float* __restrict__ bq,
    const float* __restrict__ Wk, const float* __restrict__ bk,
    const float* __restrict__ Wv, const float* __restrict__ bv,
    __half* __restrict__ xq, __half* __restrict__ xk, __half* __restrict__ xv,
    int* __restrict__ cnt)
{
    const int tid = threadIdx.x;

    // zero the histogram buffer
    const int gid = blockIdx.x * 256 + tid;
    if (gid < N_NODES) cnt[gid] = 0;

    // Wh[m][kp][c]: half2 {W[2kp][c], W[2kp+1][c]}, kp=0..31, c=0..63
    __shared__ unsigned Wh[3 * 2048];
    #pragma unroll
    for (int it = 0; it < 8; ++it) {
        const int idx = it * 256 + tid;          // 0..2047
        const int kp = idx >> 6, c = idx & 63;
        {
            const __half2 h = __floats2half2_rn(Wq[(2 * kp) * 64 + c], Wq[(2 * kp + 1) * 64 + c]);
            Wh[idx] = *reinterpret_cast<const unsigned*>(&h);
        }
        {
            const __half2 h = __floats2half2_rn(Wk[(2 * kp) * 64 + c], Wk[(2 * kp + 1) * 64 + c]);
            Wh[2048 + idx] = *reinterpret_cast<const unsigned*>(&h);
        }
        {
            const __half2 h = __floats2half2_rn(Wv[(2 * kp) * 64 + c], Wv[(2 * kp + 1) * 64 + c]);
            Wh[4096 + idx] = *reinterpret_cast<const unsigned*>(&h);
        }
    }
    __syncthreads();

    const int cg = tid & 15;
    const int rg = tid >> 4;
    const int c0 = cg * 4;
    const int base = blockIdx.x * 64 + rg * 4;

    const float* ins[3]  = {qin, kin, vin};
    const float* bs[3]   = {bq, bk, bv};
    __half*      outs[3] = {xq, xk, xv};

    int rowi[4];
    #pragma unroll
    for (int rr = 0; rr < 4; ++rr)
        rowi[rr] = (base + rr < N_NODES) ? (base + rr) : (N_NODES - 1);

    #pragma unroll
    for (int m = 0; m < 3; ++m) {
        const float* in = ins[m];
        float4 acc[4];
        const float4 b4 = *reinterpret_cast<const float4*>(&bs[m][c0]);
        #pragma unroll
        for (int rr = 0; rr < 4; ++rr) acc[rr] = b4;

        for (int kk = 0; kk < 64; kk += 4) {
            __half2 xp[4][2];
            #pragma unroll
            for (int rr = 0; rr < 4; ++rr) {
                const float4 rv = *reinterpret_cast<const float4*>(&in[rowi[rr] * 64 + kk]);
                xp[rr][0] = __floats2half2_rn(rv.x, rv.y);
                xp[rr][1] = __floats2half2_rn(rv.z, rv.w);
            }
            #pragma unroll
            for (int h = 0; h < 2; ++h) {
                const int kp = (kk >> 1) + h;
                const uint4 wq = *reinterpret_cast<const uint4*>(&Wh[m * 2048 + kp * 64 + c0]);
                const __half2 w0 = *reinterpret_cast<const __half2*>(&wq.x);
                const __half2 w1 = *reinterpret_cast<const __half2*>(&wq.y);
                const __half2 w2 = *reinterpret_cast<const __half2*>(&wq.z);
                const __half2 w3 = *reinterpret_cast<const __half2*>(&wq.w);
                #pragma unroll
                for (int rr = 0; rr < 4; ++rr) {
                    acc[rr].x = fdot2f(xp[rr][h], w0, acc[rr].x);
                    acc[rr].y = fdot2f(xp[rr][h], w1, acc[rr].y);
                    acc[rr].z = fdot2f(xp[rr][h], w2, acc[rr].z);
                    acc[rr].w = fdot2f(xp[rr][h], w3, acc[rr].w);
                }
            }
        }
        #pragma unroll
        for (int rr = 0; rr < 4; ++rr) {
            if (base + rr < N_NODES) {
                union { __half2 h[2]; uint2 u; } pk;
                pk.h[0] = __floats2half2_rn(acc[rr].x, acc[rr].y);
                pk.h[1] = __floats2half2_rn(acc[rr].z, acc[rr].w);
                *reinterpret_cast<uint2*>(&outs[m][(size_t)(base + rr) * 64 + c0]) = pk.u;
            }
        }
    }
}

// ---------------------------------------------------------------------------
// Hierarchical scan, step A: per-1024-element block sums (49 blocks).
// ---------------------------------------------------------------------------
__global__ __launch_bounds__(256) void scan_sums(
    const int* __restrict__ cnt, int* __restrict__ bsum)
{
    const int tid  = threadIdx.x;
    const int base = blockIdx.x * SCAN_TILE + tid * 4;
    int s = 0;
    if (base + 3 < N_NODES) {
        const int4 t = *reinterpret_cast<const int4*>(&cnt[base]);
        s = t.x + t.y + t.z + t.w;
    } else {
        #pragma unroll
        for (int i = 0; i < 4; ++i)
            if (base + i < N_NODES) s += cnt[base + i];
    }
    #pragma unroll
    for (int d = 1; d < 64; d <<= 1) s += __shfl_xor(s, d);
    __shared__ int ws[4];
    if ((tid & 63) == 0) ws[tid >> 6] = s;
    __syncthreads();
    if (tid == 0) bsum[blockIdx.x] = ws[0] + ws[1] + ws[2] + ws[3];
}

// ---------------------------------------------------------------------------
// Hierarchical scan, steps B+C fused: wave 0 redundantly exclusive-scans the
// 49 block sums (replaces the scan_bsum dispatch); block then does its local
// exclusive scan + offset. Writes off[] and re-purposes cnt[] as the cursor.
// ---------------------------------------------------------------------------
__global__ __launch_bounds__(256) void scan_final(
    int* __restrict__ cnt, const int* __restrict__ bsum, int* __restrict__ off)
{
    __shared__ int s_boff;
    __shared__ int wsum[4];
    const int tid  = threadIdx.x;
    const int base = blockIdx.x * SCAN_TILE + tid * 4;

    // wave 0: exclusive prefix of bsum; this block's offset -> s_boff
    if (tid < 64) {
        const int v = (tid < SCAN_NBLK) ? bsum[tid] : 0;
        int bincl = v;
        #pragma unroll
        for (int d = 1; d < 64; d <<= 1) {
            const int t = __shfl_up(bincl, d);
            if (tid >= d) bincl += t;
        }
        if (tid == blockIdx.x) s_boff = bincl - v;
    }

    int v0 = 0, v1 = 0, v2 = 0, v3 = 0;
    if (base + 3 < N_NODES) {
        const int4 t = *reinterpret_cast<const int4*>(&cnt[base]);
        v0 = t.x; v1 = t.y; v2 = t.z; v3 = t.w;
    } else {
        if (base + 0 < N_NODES) v0 = cnt[base + 0];
        if (base + 1 < N_NODES) v1 = cnt[base + 1];
        if (base + 2 < N_NODES) v2 = cnt[base + 2];
        if (base + 3 < N_NODES) v3 = cnt[base + 3];
    }
    const int s = v0 + v1 + v2 + v3;

    int incl = s;
    #pragma unroll
    for (int d = 1; d < 64; d <<= 1) {
        const int t = __shfl_up(incl, d);
        if ((tid & 63) >= d) incl += t;
    }
    const int wave = tid >> 6;
    if ((tid & 63) == 63) wsum[wave] = incl;
    __syncthreads();
    int woff = 0;
    #pragma unroll
    for (int w = 0; w < 3; ++w)
        if (w < wave) woff += wsum[w];

    int run = s_boff + woff + (incl - s);
    if (base + 0 < N_NODES) { off[base + 0] = run; cnt[base + 0] = run; run += v0; }
    if (base + 1 < N_NODES) { off[base + 1] = run; cnt[base + 1] = run; run += v1; }
    if (base + 2 < N_NODES) { off[base + 2] = run; cnt[base + 2] = run; run += v2; }
    if (base + 3 < N_NODES) { off[base + 3] = run; cnt[base + 3] = run; run += v3; }

    if (blockIdx.x == 0 && tid == 0) off[N_NODES] = E_EDGES;
}

// ---------------------------------------------------------------------------
// Edge-weights kernel (r17-proven math, EW_EPT=20, grid 1250 EXACT):
// coalesced edge-order record + histogram. p computed in-kernel from edges.
// Record: word0 = src | (dst<<16); word1 = w[0..3] u8; word2 = w[4..7] u8;
//         word3 = p (f32). Softmax without max-subtraction.
// ---------------------------------------------------------------------------
__global__ __launch_bounds__(256) void edge_weights(
    const int* __restrict__ eidx, const float* __restrict__ edges,
    const float* __restrict__ Wp, const float* __restrict__ bp,
    const float* __restrict__ W1, const float* __restrict__ b1,
    const float* __restrict__ W2, const float* __restrict__ b2,
    const __half* __restrict__ xq, const __half* __restrict__ xk,
    int* __restrict__ cnt, uint4* __restrict__ rece)
{
    const int tid  = threadIdx.x;
    const int lane = tid & 63;
    const int o    = lane >> 3;
    const int r    = lane & 7;
    const int wave = tid >> 6;

    __half2 W1h[4][8];
    #pragma unroll
    for (int i = 0; i < 4; ++i) {
        const float4 a0 = *reinterpret_cast<const float4*>(&W1[(8 * r + 2 * i) * 8]);
        const float4 a1 = *reinterpret_cast<const float4*>(&W1[(8 * r + 2 * i) * 8 + 4]);
        const float4 c0 = *reinterpret_cast<const float4*>(&W1[(8 * r + 2 * i + 1) * 8]);
        const float4 c1 = *reinterpret_cast<const float4*>(&W1[(8 * r + 2 * i + 1) * 8 + 4]);
        W1h[i][0] = __floats2half2_rn(a0.x, c0.x);
        W1h[i][1] = __floats2half2_rn(a0.y, c0.y);
        W1h[i][2] = __floats2half2_rn(a0.z, c0.z);
        W1h[i][3] = __floats2half2_rn(a0.w, c0.w);
        W1h[i][4] = __floats2half2_rn(a1.x, c1.x);
        W1h[i][5] = __floats2half2_rn(a1.y, c1.y);
        W1h[i][6] = __floats2half2_rn(a1.z, c1.z);
        W1h[i][7] = __floats2half2_rn(a1.w, c1.w);
    }
    float W2col[8];
    #pragma unroll
    for (int jj = 0; jj < 8; ++jj) W2col[jj] = W2[jj * 8 + r];
    float b1u[8];
    #pragma unroll
    for (int j = 0; j < 8; ++j) b1u[j] = sgpr_f(b1[j]);
    const float b2r = b2[r];
    const float wpA = Wp[2 * r], wpB = Wp[2 * r + 1];
    const float bp0 = sgpr_f(bp[0]);

    const int wb = (blockIdx.x * 4 + wave) * (8 * EW_EPT);

    #pragma unroll
    for (int t = 0; t < EW_EPT; ++t) {
        const int e = wb + t * 8 + o;

        const int2 sd = *reinterpret_cast<const int2*>(&eidx[2 * e]);
        const float2 e2 = *reinterpret_cast<const float2*>(&edges[(size_t)e * 16 + 2 * r]);

        uint4 q4u = *reinterpret_cast<const uint4*>(&xq[(size_t)sd.x * 64 + 8 * r]);
        uint4 k4u = *reinterpret_cast<const uint4*>(&xk[(size_t)sd.y * 64 + 8 * r]);

        float p = fmaf(e2.x, wpA, e2.y * wpB);
        p = oct_sum(p) + bp0;

        const __half2 p2 = __float2half2_rn(p);
        const __half2* qh = reinterpret_cast<const __half2*>(&q4u);
        const __half2* kh = reinterpret_cast<const __half2*>(&k4u);

        float part[8];
        #pragma unroll
        for (int jj = 0; jj < 8; ++jj) part[jj] = 0.f;
        #pragma unroll
        for (int i = 0; i < 4; ++i) {
            const __half2 d = relu_h2(__hadd2(__hsub2(kh[i], qh[i]), p2));
            #pragma unroll
            for (int jj = 0; jj < 8; ++jj)
                part[jj] = fdot2f(d, W1h[i][jj], part[jj]);
        }
        #pragma unroll
        for (int jj = 0; jj < 8; ++jj) part[jj] = oct_sum(part[jj]);

        float h2 = b2r;
        #pragma unroll
        for (int jj = 0; jj < 8; ++jj) {
            const float h1 = fmaxf(part[jj] + b1u[jj], 0.f);
            h2 = fmaf(h1, W2col[jj], h2);
        }

        // softmax without max-subtraction (|h2| << 88, f32-exp safe)
        const float ex = __expf(h2);
        const float sm = oct_sum(ex);
        const float w  = ex / sm;

        // quantize to u8 (*255, deferred 1/255 in node_accum's epilogue)
        const unsigned wu = (unsigned)__float2uint_rn(w * 255.f);
        unsigned word = wu << (8 * (r & 3));
        word |= (unsigned)dpp_mov_i32<0xB1>((int)word);   // quad or-combine
        word |= (unsigned)dpp_mov_i32<0x4E>((int)word);
        const unsigned other = (unsigned)dpp_mov_i32<0x141>((int)word); // other quad's word

        if (r == 0) {
            uint4 rec;
            rec.x = (unsigned)sd.x | ((unsigned)sd.y << 16);
            rec.y = word;    // w[0..3]
            rec.z = other;   // w[4..7]
            rec.w = __float_as_uint(p);
            rece[e] = rec;   // coalesced: 8 octets -> 128B contiguous
        }
        if (r == 1) atomicAdd(&cnt[sd.x], 1);
    }
}

// ---------------------------------------------------------------------------
// Scatter: ONE random 16B store per edge. src comes from the record.
// ---------------------------------------------------------------------------
__global__ __launch_bounds__(256) void scatter_kernel(
    const uint4* __restrict__ rece, int* __restrict__ cursor,
    uint4* __restrict__ reccsr)
{
    const int e = blockIdx.x * 256 + threadIdx.x;
    const uint4 rec = rece[e];
    const int src = (int)(rec.x & 0xFFFFu);
    const int pos = atomicAdd(&cursor[src], 1);
    reccsr[pos] = rec;
}

// ---------------------------------------------------------------------------
// Node accumulation (r14-proven): 16 lanes per node (2 sub-octets, alternate
// edges). Lane r owns channels 8r..8r+7; weights u8 with deferred 1/255.
// ---------------------------------------------------------------------------
__global__ __launch_bounds__(256) void node_accum(
    const int* __restrict__ off, const uint4* __restrict__ reccsr,
    const __half* __restrict__ xv, float* __restrict__ out)
{
    const int tid  = threadIdx.x;
    const int lane = tid & 63;
    const int grp  = lane >> 4;
    const int sub  = (lane >> 3) & 1;
    const int r    = lane & 7;
    const int wave = tid >> 6;

    const int node = blockIdx.x * 16 + wave * 4 + grp;

    const int beg = off[node];
    const int end = off[node + 1];

    float acc[8];
    #pragma unroll
    for (int i = 0; i < 8; ++i) acc[i] = 0.f;

    int j = beg + sub;
    uint4 rec;
    if (j < end) rec = reccsr[j];

    for (; j < end; j += 2) {
        const uint4 cur = rec;
        const int   dst = (int)(cur.x >> 16);
        const float p   = __uint_as_float(cur.w);

        union { uint4 u; __half2 h[4]; } v4;
        v4.u = *reinterpret_cast<const uint4*>(&xv[(size_t)dst * 64 + 8 * r]);

        if (j + 2 < end) rec = reccsr[j + 2];

        float wf[8];
        #pragma unroll
        for (int i = 0; i < 4; ++i) {
            wf[i]     = (float)((cur.y >> (8 * i)) & 255u);
            wf[4 + i] = (float)((cur.z >> (8 * i)) & 255u);
        }

        #pragma unroll
        for (int i = 0; i < 4; ++i) {
            const float2 fv = __half22float2(v4.h[i]);
            acc[2 * i]     = fmaf(fv.x + p, wf[2 * i],     acc[2 * i]);
            acc[2 * i + 1] = fmaf(fv.y + p, wf[2 * i + 1], acc[2 * i + 1]);
        }
    }

    #pragma unroll
    for (int i = 0; i < 8; ++i)
        acc[i] += __shfl_xor(acc[i], 8);

    if (sub == 0) {
        const float c = 1.f / 255.f;
        float* orow = &out[(size_t)node * 64 + 8 * r];
        *reinterpret_cast<float4*>(orow) =
            make_float4(acc[0] * c, acc[1] * c, acc[2] * c, acc[3] * c);
        *reinterpret_cast<float4*>(orow + 4) =
            make_float4(acc[4] * c, acc[5] * c, acc[6] * c, acc[7] * c);
    }
}

extern "C" void kernel_launch(void* const* d_in, const int* in_sizes, int n_in,
                              void* d_out, int out_size, void* d_ws, size_t ws_size,
                              hipStream_t stream) {
    const float* q     = (const float*)d_in[0];
    const float* k     = (const float*)d_in[1];
    const float* v     = (const float*)d_in[2];
    const float* edges = (const float*)d_in[3];
    const int*   eidx  = (const int*)d_in[4];
    const float* Wq    = (const float*)d_in[5];
    const float* bq    = (const float*)d_in[6];
    const float* Wk    = (const float*)d_in[7];
    const float* bk    = (const float*)d_in[8];
    const float* Wv    = (const float*)d_in[9];
    const float* bv    = (const float*)d_in[10];
    const float* Wp    = (const float*)d_in[11];
    const float* bp    = (const float*)d_in[12];
    const float* W1    = (const float*)d_in[13];
    const float* b1    = (const float*)d_in[14];
    const float* W2    = (const float*)d_in[15];
    const float* b2    = (const float*)d_in[16];
    float* out = (float*)d_out;

    // workspace layout
    char* ws = (char*)d_ws;
    __half* xq = (__half*)ws;          ws += (size_t)N_NODES * 64 * sizeof(__half);
    __half* xk = (__half*)ws;          ws += (size_t)N_NODES * 64 * sizeof(__half);
    __half* xv = (__half*)ws;          ws += (size_t)N_NODES * 64 * sizeof(__half);
    int* cnt  = (int*)ws;              ws += (size_t)(N_NODES + 64) * sizeof(int);
    int* off  = (int*)ws;              ws += (size_t)(N_NODES + 64) * sizeof(int);
    int* bsum = (int*)ws;              ws += (size_t)64 * sizeof(int);
    uint4* rece   = (uint4*)ws;        ws += (size_t)E_EDGES * sizeof(uint4);   // 12.8 MB
    uint4* reccsr = (uint4*)ws;        ws += (size_t)E_EDGES * sizeof(uint4);   // 12.8 MB

    // proj also zeroes cnt (memset dispatch removed)
    proj_kernel<<<dim3((N_NODES + 63) / 64), dim3(256), 0, stream>>>(
        q, k, v, Wq, bq, Wk, bk, Wv, bv, xq, xk, xv, cnt);

    edge_weights<<<dim3(E_EDGES / (32 * EW_EPT)), dim3(256), 0, stream>>>(
        eidx, edges, Wp, bp, W1, b1, W2, b2, xq, xk, cnt, rece);

    scan_sums<<<dim3(SCAN_NBLK), dim3(256), 0, stream>>>(cnt, bsum);
    scan_final<<<dim3(SCAN_NBLK), dim3(256), 0, stream>>>(cnt, bsum, off);

    scatter_kernel<<<dim3(E_EDGES / 256), dim3(256), 0, stream>>>(
        rece, cnt, reccsr);

    node_accum<<<dim3(N_NODES / 16), dim3(256), 0, stream>>>(
        off, reccsr, xv, out);
}

// Round 22
// 152.656 us; speedup vs baseline: 1.1722x; 1.0030x over previous
//
#include <hip/hip_runtime.h>
#include <hip/hip_fp16.h>

#define N_NODES 50000
#define E_EDGES 800000
#define SCAN_TILE 1024
#define SCAN_NBLK ((N_NODES + SCAN_TILE - 1) / SCAN_TILE)   // 49
#define EW_EPT 25   // edges/octet/iter: 800 edges per block -> 1000 blocks EXACT

__device__ __forceinline__ float sgpr_f(float x) {
    return __uint_as_float(__builtin_amdgcn_readfirstlane(__float_as_uint(x)));
}

#if defined(__has_builtin)
#if __has_builtin(__builtin_amdgcn_fdot2)
#define HAS_FDOT2 1
#endif
#endif

typedef _Float16 v2h_t __attribute__((ext_vector_type(2)));

__device__ __forceinline__ float fdot2f(__half2 a, __half2 b, float c) {
#ifdef HAS_FDOT2
    return __builtin_amdgcn_fdot2(*reinterpret_cast<v2h_t*>(&a),
                                  *reinterpret_cast<v2h_t*>(&b), c, false);
#else
    const float2 fa = __half22float2(a);
    const float2 fb = __half22float2(b);
    return fmaf(fa.x, fb.x, fmaf(fa.y, fb.y, c));
#endif
}

// packed relu: v_pk_max_f16 with inline constant 0
__device__ __forceinline__ __half2 relu_h2(__half2 x) {
    union { __half2 h; unsigned u; } a, r;
    a.h = x;
    asm("v_pk_max_f16 %0, %1, 0" : "=v"(r.u) : "v"(a.u));
    return r.h;
}

// DPP cross-lane moves (VALU pipe, no LDS).
// 0xB1 = quad_perm lane^1, 0x4E = quad_perm lane^2,
// 0x141 = ROW_HALF_MIRROR (lane i <-> 7-i within aligned 8-lane groups).
template <int CTRL>
__device__ __forceinline__ float dpp_mov_f32(float x) {
    return __int_as_float(__builtin_amdgcn_update_dpp(
        0, __float_as_int(x), CTRL, 0xF, 0xF, true));
}
template <int CTRL>
__device__ __forceinline__ int dpp_mov_i32(int x) {
    return __builtin_amdgcn_update_dpp(0, x, CTRL, 0xF, 0xF, true);
}
// full 8-lane (octet) all-reduce (validated r11)
__device__ __forceinline__ float oct_sum(float x) {
    x += dpp_mov_f32<0xB1>(x);
    x += dpp_mov_f32<0x4E>(x);
    x += dpp_mov_f32<0x141>(x);
    return x;
}

// ---------------------------------------------------------------------------
// Projection kernel, fp16-dot2 version (r16-proven): W staged in LDS as half2
// k-pairs (24 KB), inputs converted to half2, fdot2 with f32 accumulate.
// Also zeroes cnt[] (replaces the memset dispatch).
// ---------------------------------------------------------------------------
__global__ __launch_bounds__(256) void proj_kernel(
    const float* __restrict__ qin, const float* __restrict__ kin, const float* __restrict__ vin,
    const float* __restrict__ Wq, const float* __restrict__ bq,
    const float* __restrict__ Wk, const float* __restrict__ bk,
    const float* __restrict__ Wv, const float* __restrict__ bv,
    __half* __restrict__ xq, __half* __restrict__ xk, __half* __restrict__ xv,
    int* __restrict__ cnt)
{
    const int tid = threadIdx.x;

    // zero the histogram buffer
    const int gid = blockIdx.x * 256 + tid;
    if (gid < N_NODES) cnt[gid] = 0;

    // Wh[m][kp][c]: half2 {W[2kp][c], W[2kp+1][c]}, kp=0..31, c=0..63
    __shared__ unsigned Wh[3 * 2048];
    #pragma unroll
    for (int it = 0; it < 8; ++it) {
        const int idx = it * 256 + tid;          // 0..2047
        const int kp = idx >> 6, c = idx & 63;
        {
            const __half2 h = __floats2half2_rn(Wq[(2 * kp) * 64 + c], Wq[(2 * kp + 1) * 64 + c]);
            Wh[idx] = *reinterpret_cast<const unsigned*>(&h);
        }
        {
            const __half2 h = __floats2half2_rn(Wk[(2 * kp) * 64 + c], Wk[(2 * kp + 1) * 64 + c]);
            Wh[2048 + idx] = *reinterpret_cast<const unsigned*>(&h);
        }
        {
            const __half2 h = __floats2half2_rn(Wv[(2 * kp) * 64 + c], Wv[(2 * kp + 1) * 64 + c]);
            Wh[4096 + idx] = *reinterpret_cast<const unsigned*>(&h);
        }
    }
    __syncthreads();

    const int cg = tid & 15;
    const int rg = tid >> 4;
    const int c0 = cg * 4;
    const int base = blockIdx.x * 64 + rg * 4;

    const float* ins[3]  = {qin, kin, vin};
    const float* bs[3]   = {bq, bk, bv};
    __half*      outs[3] = {xq, xk, xv};

    int rowi[4];
    #pragma unroll
    for (int rr = 0; rr < 4; ++rr)
        rowi[rr] = (base + rr < N_NODES) ? (base + rr) : (N_NODES - 1);

    #pragma unroll
    for (int m = 0; m < 3; ++m) {
        const float* in = ins[m];
        float4 acc[4];
        const float4 b4 = *reinterpret_cast<const float4*>(&bs[m][c0]);
        #pragma unroll
        for (int rr = 0; rr < 4; ++rr) acc[rr] = b4;

        for (int kk = 0; kk < 64; kk += 4) {
            __half2 xp[4][2];
            #pragma unroll
            for (int rr = 0; rr < 4; ++rr) {
                const float4 rv = *reinterpret_cast<const float4*>(&in[rowi[rr] * 64 + kk]);
                xp[rr][0] = __floats2half2_rn(rv.x, rv.y);
                xp[rr][1] = __floats2half2_rn(rv.z, rv.w);
            }
            #pragma unroll
            for (int h = 0; h < 2; ++h) {
                const int kp = (kk >> 1) + h;
                const uint4 wq = *reinterpret_cast<const uint4*>(&Wh[m * 2048 + kp * 64 + c0]);
                const __half2 w0 = *reinterpret_cast<const __half2*>(&wq.x);
                const __half2 w1 = *reinterpret_cast<const __half2*>(&wq.y);
                const __half2 w2 = *reinterpret_cast<const __half2*>(&wq.z);
                const __half2 w3 = *reinterpret_cast<const __half2*>(&wq.w);
                #pragma unroll
                for (int rr = 0; rr < 4; ++rr) {
                    acc[rr].x = fdot2f(xp[rr][h], w0, acc[rr].x);
                    acc[rr].y = fdot2f(xp[rr][h], w1, acc[rr].y);
                    acc[rr].z = fdot2f(xp[rr][h], w2, acc[rr].z);
                    acc[rr].w = fdot2f(xp[rr][h], w3, acc[rr].w);
                }
            }
        }
        #pragma unroll
        for (int rr = 0; rr < 4; ++rr) {
            if (base + rr < N_NODES) {
                union { __half2 h[2]; uint2 u; } pk;
                pk.h[0] = __floats2half2_rn(acc[rr].x, acc[rr].y);
                pk.h[1] = __floats2half2_rn(acc[rr].z, acc[rr].w);
                *reinterpret_cast<uint2*>(&outs[m][(size_t)(base + rr) * 64 + c0]) = pk.u;
            }
        }
    }
}

// ---------------------------------------------------------------------------
// Hierarchical scan, step A: per-1024-element block sums (49 blocks).
// ---------------------------------------------------------------------------
__global__ __launch_bounds__(256) void scan_sums(
    const int* __restrict__ cnt, int* __restrict__ bsum)
{
    const int tid  = threadIdx.x;
    const int base = blockIdx.x * SCAN_TILE + tid * 4;
    int s = 0;
    if (base + 3 < N_NODES) {
        const int4 t = *reinterpret_cast<const int4*>(&cnt[base]);
        s = t.x + t.y + t.z + t.w;
    } else {
        #pragma unroll
        for (int i = 0; i < 4; ++i)
            if (base + i < N_NODES) s += cnt[base + i];
    }
    #pragma unroll
    for (int d = 1; d < 64; d <<= 1) s += __shfl_xor(s, d);
    __shared__ int ws[4];
    if ((tid & 63) == 0) ws[tid >> 6] = s;
    __syncthreads();
    if (tid == 0) bsum[blockIdx.x] = ws[0] + ws[1] + ws[2] + ws[3];
}

// ---------------------------------------------------------------------------
// Hierarchical scan, steps B+C fused (r21-proven): wave 0 redundantly scans
// the 49 block sums; block then does its local exclusive scan + offset.
// Writes off[] and re-purposes cnt[] as the scatter cursor.
// ---------------------------------------------------------------------------
__global__ __launch_bounds__(256) void scan_final(
    int* __restrict__ cnt, const int* __restrict__ bsum, int* __restrict__ off)
{
    __shared__ int s_boff;
    __shared__ int wsum[4];
    const int tid  = threadIdx.x;
    const int base = blockIdx.x * SCAN_TILE + tid * 4;

    // wave 0: exclusive prefix of bsum; this block's offset -> s_boff
    if (tid < 64) {
        const int v = (tid < SCAN_NBLK) ? bsum[tid] : 0;
        int bincl = v;
        #pragma unroll
        for (int d = 1; d < 64; d <<= 1) {
            const int t = __shfl_up(bincl, d);
            if (tid >= d) bincl += t;
        }
        if (tid == blockIdx.x) s_boff = bincl - v;
    }

    int v0 = 0, v1 = 0, v2 = 0, v3 = 0;
    if (base + 3 < N_NODES) {
        const int4 t = *reinterpret_cast<const int4*>(&cnt[base]);
        v0 = t.x; v1 = t.y; v2 = t.z; v3 = t.w;
    } else {
        if (base + 0 < N_NODES) v0 = cnt[base + 0];
        if (base + 1 < N_NODES) v1 = cnt[base + 1];
        if (base + 2 < N_NODES) v2 = cnt[base + 2];
        if (base + 3 < N_NODES) v3 = cnt[base + 3];
    }
    const int s = v0 + v1 + v2 + v3;

    int incl = s;
    #pragma unroll
    for (int d = 1; d < 64; d <<= 1) {
        const int t = __shfl_up(incl, d);
        if ((tid & 63) >= d) incl += t;
    }
    const int wave = tid >> 6;
    if ((tid & 63) == 63) wsum[wave] = incl;
    __syncthreads();
    int woff = 0;
    #pragma unroll
    for (int w = 0; w < 3; ++w)
        if (w < wave) woff += wsum[w];

    int run = s_boff + woff + (incl - s);
    if (base + 0 < N_NODES) { off[base + 0] = run; cnt[base + 0] = run; run += v0; }
    if (base + 1 < N_NODES) { off[base + 1] = run; cnt[base + 1] = run; run += v1; }
    if (base + 2 < N_NODES) { off[base + 2] = run; cnt[base + 2] = run; run += v2; }
    if (base + 3 < N_NODES) { off[base + 3] = run; cnt[base + 3] = run; run += v3; }

    if (blockIdx.x == 0 && tid == 0) off[N_NODES] = E_EDGES;
}

// ---------------------------------------------------------------------------
// Edge-weights kernel (r17-proven math, EW_EPT=25, grid 1000 EXACT):
// coalesced edge-order record + histogram. p computed in-kernel from edges.
// Record: word0 = src | (dst<<16); word1 = w[0..3] u8; word2 = w[4..7] u8;
//         word3 = p (f32). Softmax without max-subtraction.
// ---------------------------------------------------------------------------
__global__ __launch_bounds__(256) void edge_weights(
    const int* __restrict__ eidx, const float* __restrict__ edges,
    const float* __restrict__ Wp, const float* __restrict__ bp,
    const float* __restrict__ W1, const float* __restrict__ b1,
    const float* __restrict__ W2, const float* __restrict__ b2,
    const __half* __restrict__ xq, const __half* __restrict__ xk,
    int* __restrict__ cnt, uint4* __restrict__ rece)
{
    const int tid  = threadIdx.x;
    const int lane = tid & 63;
    const int o    = lane >> 3;
    const int r    = lane & 7;
    const int wave = tid >> 6;

    __half2 W1h[4][8];
    #pragma unroll
    for (int i = 0; i < 4; ++i) {
        const float4 a0 = *reinterpret_cast<const float4*>(&W1[(8 * r + 2 * i) * 8]);
        const float4 a1 = *reinterpret_cast<const float4*>(&W1[(8 * r + 2 * i) * 8 + 4]);
        const float4 c0 = *reinterpret_cast<const float4*>(&W1[(8 * r + 2 * i + 1) * 8]);
        const float4 c1 = *reinterpret_cast<const float4*>(&W1[(8 * r + 2 * i + 1) * 8 + 4]);
        W1h[i][0] = __floats2half2_rn(a0.x, c0.x);
        W1h[i][1] = __floats2half2_rn(a0.y, c0.y);
        W1h[i][2] = __floats2half2_rn(a0.z, c0.z);
        W1h[i][3] = __floats2half2_rn(a0.w, c0.w);
        W1h[i][4] = __floats2half2_rn(a1.x, c1.x);
        W1h[i][5] = __floats2half2_rn(a1.y, c1.y);
        W1h[i][6] = __floats2half2_rn(a1.z, c1.z);
        W1h[i][7] = __floats2half2_rn(a1.w, c1.w);
    }
    float W2col[8];
    #pragma unroll
    for (int jj = 0; jj < 8; ++jj) W2col[jj] = W2[jj * 8 + r];
    float b1u[8];
    #pragma unroll
    for (int j = 0; j < 8; ++j) b1u[j] = sgpr_f(b1[j]);
    const float b2r = b2[r];
    const float wpA = Wp[2 * r], wpB = Wp[2 * r + 1];
    const float bp0 = sgpr_f(bp[0]);

    const int wb = (blockIdx.x * 4 + wave) * (8 * EW_EPT);

    #pragma unroll
    for (int t = 0; t < EW_EPT; ++t) {
        const int e = wb + t * 8 + o;

        const int2 sd = *reinterpret_cast<const int2*>(&eidx[2 * e]);
        const float2 e2 = *reinterpret_cast<const float2*>(&edges[(size_t)e * 16 + 2 * r]);

        uint4 q4u = *reinterpret_cast<const uint4*>(&xq[(size_t)sd.x * 64 + 8 * r]);
        uint4 k4u = *reinterpret_cast<const uint4*>(&xk[(size_t)sd.y * 64 + 8 * r]);

        float p = fmaf(e2.x, wpA, e2.y * wpB);
        p = oct_sum(p) + bp0;

        const __half2 p2 = __float2half2_rn(p);
        const __half2* qh = reinterpret_cast<const __half2*>(&q4u);
        const __half2* kh = reinterpret_cast<const __half2*>(&k4u);

        float part[8];
        #pragma unroll
        for (int jj = 0; jj < 8; ++jj) part[jj] = 0.f;
        #pragma unroll
        for (int i = 0; i < 4; ++i) {
            const __half2 d = relu_h2(__hadd2(__hsub2(kh[i], qh[i]), p2));
            #pragma unroll
            for (int jj = 0; jj < 8; ++jj)
                part[jj] = fdot2f(d, W1h[i][jj], part[jj]);
        }
        #pragma unroll
        for (int jj = 0; jj < 8; ++jj) part[jj] = oct_sum(part[jj]);

        float h2 = b2r;
        #pragma unroll
        for (int jj = 0; jj < 8; ++jj) {
            const float h1 = fmaxf(part[jj] + b1u[jj], 0.f);
            h2 = fmaf(h1, W2col[jj], h2);
        }

        // softmax without max-subtraction (|h2| << 88, f32-exp safe)
        const float ex = __expf(h2);
        const float sm = oct_sum(ex);
        const float w  = ex / sm;

        // quantize to u8 (*255, deferred 1/255 in node_accum's epilogue)
        const unsigned wu = (unsigned)__float2uint_rn(w * 255.f);
        unsigned word = wu << (8 * (r & 3));
        word |= (unsigned)dpp_mov_i32<0xB1>((int)word);   // quad or-combine
        word |= (unsigned)dpp_mov_i32<0x4E>((int)word);
        const unsigned other = (unsigned)dpp_mov_i32<0x141>((int)word); // other quad's word

        if (r == 0) {
            uint4 rec;
            rec.x = (unsigned)sd.x | ((unsigned)sd.y << 16);
            rec.y = word;    // w[0..3]
            rec.z = other;   // w[4..7]
            rec.w = __float_as_uint(p);
            rece[e] = rec;   // coalesced: 8 octets -> 128B contiguous
        }
        if (r == 1) atomicAdd(&cnt[sd.x], 1);
    }
}

// ---------------------------------------------------------------------------
// Scatter: ONE random 16B store per edge. src comes from the record.
// ---------------------------------------------------------------------------
__global__ __launch_bounds__(256) void scatter_kernel(
    const uint4* __restrict__ rece, int* __restrict__ cursor,
    uint4* __restrict__ reccsr)
{
    const int e = blockIdx.x * 256 + threadIdx.x;
    const uint4 rec = rece[e];
    const int src = (int)(rec.x & 0xFFFFu);
    const int pos = atomicAdd(&cursor[src], 1);
    reccsr[pos] = rec;
}

// ---------------------------------------------------------------------------
// Node accumulation, 2-wide unrolled: 16 lanes per node (2 sub-octets,
// alternate edges). Per main iteration each sub-octet processes TWO records
// (j, j+2) with both xv gathers issued back-to-back (2x memory-level
// parallelism). Scalar tail loop. Weights u8 with deferred 1/255.
// ---------------------------------------------------------------------------
__global__ __launch_bounds__(256) void node_accum(
    const int* __restrict__ off, const uint4* __restrict__ reccsr,
    const __half* __restrict__ xv, float* __restrict__ out)
{
    const int tid  = threadIdx.x;
    const int lane = tid & 63;
    const int grp  = lane >> 4;
    const int sub  = (lane >> 3) & 1;
    const int r    = lane & 7;
    const int wave = tid >> 6;

    const int node = blockIdx.x * 16 + wave * 4 + grp;

    const int beg = off[node];
    const int end = off[node + 1];

    float acc[8];
    #pragma unroll
    for (int i = 0; i < 8; ++i) acc[i] = 0.f;

    int j = beg + sub;

    // main loop: two records per iteration, independent gather chains
    for (; j + 2 < end; j += 4) {
        const uint4 c0 = reccsr[j];
        const uint4 c1 = reccsr[j + 2];
        const int   dst0 = (int)(c0.x >> 16);
        const int   dst1 = (int)(c1.x >> 16);
        const float p0 = __uint_as_float(c0.w);
        const float p1 = __uint_as_float(c1.w);

        union { uint4 u; __half2 h[4]; } va, vb;
        va.u = *reinterpret_cast<const uint4*>(&xv[(size_t)dst0 * 64 + 8 * r]);
        vb.u = *reinterpret_cast<const uint4*>(&xv[(size_t)dst1 * 64 + 8 * r]);

        #pragma unroll
        for (int i = 0; i < 4; ++i) {
            const float2 fa = __half22float2(va.h[i]);
            const float2 fb = __half22float2(vb.h[i]);
            const float wa0 = (float)(((i < 2 ? c0.y : c0.z) >> (8 * ((2 * i) & 3))) & 255u);
            const float wa1 = (float)(((i < 2 ? c0.y : c0.z) >> (8 * ((2 * i + 1) & 3))) & 255u);
            const float wb0 = (float)(((i < 2 ? c1.y : c1.z) >> (8 * ((2 * i) & 3))) & 255u);
            const float wb1 = (float)(((i < 2 ? c1.y : c1.z) >> (8 * ((2 * i + 1) & 3))) & 255u);
            acc[2 * i]     = fmaf(fa.x + p0, wa0, acc[2 * i]);
            acc[2 * i + 1] = fmaf(fa.y + p0, wa1, acc[2 * i + 1]);
            acc[2 * i]     = fmaf(fb.x + p1, wb0, acc[2 * i]);
            acc[2 * i + 1] = fmaf(fb.y + p1, wb1, acc[2 * i + 1]);
        }
    }

    // tail: at most one record left for this sub-octet
    for (; j < end; j += 2) {
        const uint4 cur = reccsr[j];
        const int   dst = (int)(cur.x >> 16);
        const float p   = __uint_as_float(cur.w);

        union { uint4 u; __half2 h[4]; } v4;
        v4.u = *reinterpret_cast<const uint4*>(&xv[(size_t)dst * 64 + 8 * r]);

        #pragma unroll
        for (int i = 0; i < 4; ++i) {
            const float2 fv = __half22float2(v4.h[i]);
            const float w0 = (float)(((i < 2 ? cur.y : cur.z) >> (8 * ((2 * i) & 3))) & 255u);
            const float w1 = (float)(((i < 2 ? cur.y : cur.z) >> (8 * ((2 * i + 1) & 3))) & 255u);
            acc[2 * i]     = fmaf(fv.x + p, w0, acc[2 * i]);
            acc[2 * i + 1] = fmaf(fv.y + p, w1, acc[2 * i + 1]);
        }
    }

    #pragma unroll
    for (int i = 0; i < 8; ++i)
        acc[i] += __shfl_xor(acc[i], 8);

    if (sub == 0) {
        const float c = 1.f / 255.f;
        float* orow = &out[(size_t)node * 64 + 8 * r];
        *reinterpret_cast<float4*>(orow) =
            make_float4(acc[0] * c, acc[1] * c, acc[2] * c, acc[3] * c);
        *reinterpret_cast<float4*>(orow + 4) =
            make_float4(acc[4] * c, acc[5] * c, acc[6] * c, acc[7] * c);
    }
}

extern "C" void kernel_launch(void* const* d_in, const int* in_sizes, int n_in,
                              void* d_out, int out_size, void* d_ws, size_t ws_size,
                              hipStream_t stream) {
    const float* q     = (const float*)d_in[0];
    const float* k     = (const float*)d_in[1];
    const float* v     = (const float*)d_in[2];
    const float* edges = (const float*)d_in[3];
    const int*   eidx  = (const int*)d_in[4];
    const float* Wq    = (const float*)d_in[5];
    const float* bq    = (const float*)d_in[6];
    const float* Wk    = (const float*)d_in[7];
    const float* bk    = (const float*)d_in[8];
    const float* Wv    = (const float*)d_in[9];
    const float* bv    = (const float*)d_in[10];
    const float* Wp    = (const float*)d_in[11];
    const float* bp    = (const float*)d_in[12];
    const float* W1    = (const float*)d_in[13];
    const float* b1    = (const float*)d_in[14];
    const float* W2    = (const float*)d_in[15];
    const float* b2    = (const float*)d_in[16];
    float* out = (float*)d_out;

    // workspace layout
    char* ws = (char*)d_ws;
    __half* xq = (__half*)ws;          ws += (size_t)N_NODES * 64 * sizeof(__half);
    __half* xk = (__half*)ws;          ws += (size_t)N_NODES * 64 * sizeof(__half);
    __half* xv = (__half*)ws;          ws += (size_t)N_NODES * 64 * sizeof(__half);
    int* cnt  = (int*)ws;              ws += (size_t)(N_NODES + 64) * sizeof(int);
    int* off  = (int*)ws;              ws += (size_t)(N_NODES + 64) * sizeof(int);
    int* bsum = (int*)ws;              ws += (size_t)64 * sizeof(int);
    uint4* rece   = (uint4*)ws;        ws += (size_t)E_EDGES * sizeof(uint4);   // 12.8 MB
    uint4* reccsr = (uint4*)ws;        ws += (size_t)E_EDGES * sizeof(uint4);   // 12.8 MB

    // proj also zeroes cnt (memset dispatch removed)
    proj_kernel<<<dim3((N_NODES + 63) / 64), dim3(256), 0, stream>>>(
        q, k, v, Wq, bq, Wk, bk, Wv, bv, xq, xk, xv, cnt);

    edge_weights<<<dim3(E_EDGES / (32 * EW_EPT)), dim3(256), 0, stream>>>(
        eidx, edges, Wp, bp, W1, b1, W2, b2, xq, xk, cnt, rece);

    scan_sums<<<dim3(SCAN_NBLK), dim3(256), 0, stream>>>(cnt, bsum);
    scan_final<<<dim3(SCAN_NBLK), dim3(256), 0, stream>>>(cnt, bsum, off);

    scatter_kernel<<<dim3(E_EDGES / 256), dim3(256), 0, stream>>>(
        rece, cnt, reccsr);

    node_accum<<<dim3(N_NODES / 16), dim3(256), 0, stream>>>(
        off, reccsr, xv, out);
}

// Round 23
// 150.505 us; speedup vs baseline: 1.1890x; 1.0143x over previous
//
#include <hip/hip_runtime.h>
#include <hip/hip_fp16.h>

#define N_NODES 50000
#define E_EDGES 800000
#define SCAN_TILE 1024
#define SCAN_NBLK ((N_NODES + SCAN_TILE - 1) / SCAN_TILE)   // 49
#define EW_EPT 20   // edges/octet/iter: 640 edges per block -> 1250 blocks EXACT

__device__ __forceinline__ float sgpr_f(float x) {
    return __uint_as_float(__builtin_amdgcn_readfirstlane(__float_as_uint(x)));
}

#if defined(__has_builtin)
#if __has_builtin(__builtin_amdgcn_fdot2)
#define HAS_FDOT2 1
#endif
#endif

typedef _Float16 v2h_t __attribute__((ext_vector_type(2)));

__device__ __forceinline__ float fdot2f(__half2 a, __half2 b, float c) {
#ifdef HAS_FDOT2
    return __builtin_amdgcn_fdot2(*reinterpret_cast<v2h_t*>(&a),
                                  *reinterpret_cast<v2h_t*>(&b), c, false);
#else
    const float2 fa = __half22float2(a);
    const float2 fb = __half22float2(b);
    return fmaf(fa.x, fb.x, fmaf(fa.y, fb.y, c));
#endif
}

// packed relu: v_pk_max_f16 with inline constant 0
__device__ __forceinline__ __half2 relu_h2(__half2 x) {
    union { __half2 h; unsigned u; } a, r;
    a.h = x;
    asm("v_pk_max_f16 %0, %1, 0" : "=v"(r.u) : "v"(a.u));
    return r.h;
}

// DPP cross-lane moves (VALU pipe, no LDS).
// 0xB1 = quad_perm lane^1, 0x4E = quad_perm lane^2,
// 0x141 = ROW_HALF_MIRROR (lane i <-> 7-i within aligned 8-lane groups).
template <int CTRL>
__device__ __forceinline__ float dpp_mov_f32(float x) {
    return __int_as_float(__builtin_amdgcn_update_dpp(
        0, __float_as_int(x), CTRL, 0xF, 0xF, true));
}
template <int CTRL>
__device__ __forceinline__ int dpp_mov_i32(int x) {
    return __builtin_amdgcn_update_dpp(0, x, CTRL, 0xF, 0xF, true);
}
// full 8-lane (octet) all-reduce (validated r11)
__device__ __forceinline__ float oct_sum(float x) {
    x += dpp_mov_f32<0xB1>(x);
    x += dpp_mov_f32<0x4E>(x);
    x += dpp_mov_f32<0x141>(x);
    return x;
}

// ---------------------------------------------------------------------------
// Projection kernel, fp16-dot2 version (r16-proven): W staged in LDS as half2
// k-pairs (24 KB), inputs converted to half2, fdot2 with f32 accumulate.
// Also zeroes cnt[] (replaces the memset dispatch).
// ---------------------------------------------------------------------------
__global__ __launch_bounds__(256) void proj_kernel(
    const float* __restrict__ qin, const float* __restrict__ kin, const float* __restrict__ vin,
    const float* __restrict__ Wq, const float* __restrict__ bq,
    const float* __restrict__ Wk, const float* __restrict__ bk,
    const float* __restrict__ Wv, const float* __restrict__ bv,
    __half* __restrict__ xq, __half* __restrict__ xk, __half* __restrict__ xv,
    int* __restrict__ cnt)
{
    const int tid = threadIdx.x;

    // zero the histogram buffer
    const int gid = blockIdx.x * 256 + tid;
    if (gid < N_NODES) cnt[gid] = 0;

    // Wh[m][kp][c]: half2 {W[2kp][c], W[2kp+1][c]}, kp=0..31, c=0..63
    __shared__ unsigned Wh[3 * 2048];
    #pragma unroll
    for (int it = 0; it < 8; ++it) {
        const int idx = it * 256 + tid;          // 0..2047
        const int kp = idx >> 6, c = idx & 63;
        {
            const __half2 h = __floats2half2_rn(Wq[(2 * kp) * 64 + c], Wq[(2 * kp + 1) * 64 + c]);
            Wh[idx] = *reinterpret_cast<const unsigned*>(&h);
        }
        {
            const __half2 h = __floats2half2_rn(Wk[(2 * kp) * 64 + c], Wk[(2 * kp + 1) * 64 + c]);
            Wh[2048 + idx] = *reinterpret_cast<const unsigned*>(&h);
        }
        {
            const __half2 h = __floats2half2_rn(Wv[(2 * kp) * 64 + c], Wv[(2 * kp + 1) * 64 + c]);
            Wh[4096 + idx] = *reinterpret_cast<const unsigned*>(&h);
        }
    }
    __syncthreads();

    const int cg = tid & 15;
    const int rg = tid >> 4;
    const int c0 = cg * 4;
    const int base = blockIdx.x * 64 + rg * 4;

    const float* ins[3]  = {qin, kin, vin};
    const float* bs[3]   = {bq, bk, bv};
    __half*      outs[3] = {xq, xk, xv};

    int rowi[4];
    #pragma unroll
    for (int rr = 0; rr < 4; ++rr)
        rowi[rr] = (base + rr < N_NODES) ? (base + rr) : (N_NODES - 1);

    #pragma unroll
    for (int m = 0; m < 3; ++m) {
        const float* in = ins[m];
        float4 acc[4];
        const float4 b4 = *reinterpret_cast<const float4*>(&bs[m][c0]);
        #pragma unroll
        for (int rr = 0; rr < 4; ++rr) acc[rr] = b4;

        for (int kk = 0; kk < 64; kk += 4) {
            __half2 xp[4][2];
            #pragma unroll
            for (int rr = 0; rr < 4; ++rr) {
                const float4 rv = *reinterpret_cast<const float4*>(&in[rowi[rr] * 64 + kk]);
                xp[rr][0] = __floats2half2_rn(rv.x, rv.y);
                xp[rr][1] = __floats2half2_rn(rv.z, rv.w);
            }
            #pragma unroll
            for (int h = 0; h < 2; ++h) {
                const int kp = (kk >> 1) + h;
                const uint4 wq = *reinterpret_cast<const uint4*>(&Wh[m * 2048 + kp * 64 + c0]);
                const __half2 w0 = *reinterpret_cast<const __half2*>(&wq.x);
                const __half2 w1 = *reinterpret_cast<const __half2*>(&wq.y);
                const __half2 w2 = *reinterpret_cast<const __half2*>(&wq.z);
                const __half2 w3 = *reinterpret_cast<const __half2*>(&wq.w);
                #pragma unroll
                for (int rr = 0; rr < 4; ++rr) {
                    acc[rr].x = fdot2f(xp[rr][h], w0, acc[rr].x);
                    acc[rr].y = fdot2f(xp[rr][h], w1, acc[rr].y);
                    acc[rr].z = fdot2f(xp[rr][h], w2, acc[rr].z);
                    acc[rr].w = fdot2f(xp[rr][h], w3, acc[rr].w);
                }
            }
        }
        #pragma unroll
        for (int rr = 0; rr < 4; ++rr) {
            if (base + rr < N_NODES) {
                union { __half2 h[2]; uint2 u; } pk;
                pk.h[0] = __floats2half2_rn(acc[rr].x, acc[rr].y);
                pk.h[1] = __floats2half2_rn(acc[rr].z, acc[rr].w);
                *reinterpret_cast<uint2*>(&outs[m][(size_t)(base + rr) * 64 + c0]) = pk.u;
            }
        }
    }
}

// ---------------------------------------------------------------------------
// Hierarchical scan, step A: per-1024-element block sums (49 blocks).
// ---------------------------------------------------------------------------
__global__ __launch_bounds__(256) void scan_sums(
    const int* __restrict__ cnt, int* __restrict__ bsum)
{
    const int tid  = threadIdx.x;
    const int base = blockIdx.x * SCAN_TILE + tid * 4;
    int s = 0;
    if (base + 3 < N_NODES) {
        const int4 t = *reinterpret_cast<const int4*>(&cnt[base]);
        s = t.x + t.y + t.z + t.w;
    } else {
        #pragma unroll
        for (int i = 0; i < 4; ++i)
            if (base + i < N_NODES) s += cnt[base + i];
    }
    #pragma unroll
    for (int d = 1; d < 64; d <<= 1) s += __shfl_xor(s, d);
    __shared__ int ws[4];
    if ((tid & 63) == 0) ws[tid >> 6] = s;
    __syncthreads();
    if (tid == 0) bsum[blockIdx.x] = ws[0] + ws[1] + ws[2] + ws[3];
}

// ---------------------------------------------------------------------------
// Hierarchical scan, steps B+C fused (r21-proven): wave 0 redundantly scans
// the 49 block sums; block then does its local exclusive scan + offset.
// Writes off[] and re-purposes cnt[] as the scatter cursor.
// ---------------------------------------------------------------------------
__global__ __launch_bounds__(256) void scan_final(
    int* __restrict__ cnt, const int* __restrict__ bsum, int* __restrict__ off)
{
    __shared__ int s_boff;
    __shared__ int wsum[4];
    const int tid  = threadIdx.x;
    const int base = blockIdx.x * SCAN_TILE + tid * 4;

    // wave 0: exclusive prefix of bsum; this block's offset -> s_boff
    if (tid < 64) {
        const int v = (tid < SCAN_NBLK) ? bsum[tid] : 0;
        int bincl = v;
        #pragma unroll
        for (int d = 1; d < 64; d <<= 1) {
            const int t = __shfl_up(bincl, d);
            if (tid >= d) bincl += t;
        }
        if (tid == blockIdx.x) s_boff = bincl - v;
    }

    int v0 = 0, v1 = 0, v2 = 0, v3 = 0;
    if (base + 3 < N_NODES) {
        const int4 t = *reinterpret_cast<const int4*>(&cnt[base]);
        v0 = t.x; v1 = t.y; v2 = t.z; v3 = t.w;
    } else {
        if (base + 0 < N_NODES) v0 = cnt[base + 0];
        if (base + 1 < N_NODES) v1 = cnt[base + 1];
        if (base + 2 < N_NODES) v2 = cnt[base + 2];
        if (base + 3 < N_NODES) v3 = cnt[base + 3];
    }
    const int s = v0 + v1 + v2 + v3;

    int incl = s;
    #pragma unroll
    for (int d = 1; d < 64; d <<= 1) {
        const int t = __shfl_up(incl, d);
        if ((tid & 63) >= d) incl += t;
    }
    const int wave = tid >> 6;
    if ((tid & 63) == 63) wsum[wave] = incl;
    __syncthreads();
    int woff = 0;
    #pragma unroll
    for (int w = 0; w < 3; ++w)
        if (w < wave) woff += wsum[w];

    int run = s_boff + woff + (incl - s);
    if (base + 0 < N_NODES) { off[base + 0] = run; cnt[base + 0] = run; run += v0; }
    if (base + 1 < N_NODES) { off[base + 1] = run; cnt[base + 1] = run; run += v1; }
    if (base + 2 < N_NODES) { off[base + 2] = run; cnt[base + 2] = run; run += v2; }
    if (base + 3 < N_NODES) { off[base + 3] = run; cnt[base + 3] = run; run += v3; }

    if (blockIdx.x == 0 && tid == 0) off[N_NODES] = E_EDGES;
}

// ---------------------------------------------------------------------------
// Edge-weights kernel (r17-proven math, EW_EPT=20, grid 1250 EXACT):
// coalesced edge-order record + histogram. p computed in-kernel from edges.
// Record: word0 = src | (dst<<16); word1 = w[0..3] u8; word2 = w[4..7] u8;
//         word3 = p (f32). Softmax without max-subtraction.
// ---------------------------------------------------------------------------
__global__ __launch_bounds__(256) void edge_weights(
    const int* __restrict__ eidx, const float* __restrict__ edges,
    const float* __restrict__ Wp, const float* __restrict__ bp,
    const float* __restrict__ W1, const float* __restrict__ b1,
    const float* __restrict__ W2, const float* __restrict__ b2,
    const __half* __restrict__ xq, const __half* __restrict__ xk,
    int* __restrict__ cnt, uint4* __restrict__ rece)
{
    const int tid  = threadIdx.x;
    const int lane = tid & 63;
    const int o    = lane >> 3;
    const int r    = lane & 7;
    const int wave = tid >> 6;

    __half2 W1h[4][8];
    #pragma unroll
    for (int i = 0; i < 4; ++i) {
        const float4 a0 = *reinterpret_cast<const float4*>(&W1[(8 * r + 2 * i) * 8]);
        const float4 a1 = *reinterpret_cast<const float4*>(&W1[(8 * r + 2 * i) * 8 + 4]);
        const float4 c0 = *reinterpret_cast<const float4*>(&W1[(8 * r + 2 * i + 1) * 8]);
        const float4 c1 = *reinterpret_cast<const float4*>(&W1[(8 * r + 2 * i + 1) * 8 + 4]);
        W1h[i][0] = __floats2half2_rn(a0.x, c0.x);
        W1h[i][1] = __floats2half2_rn(a0.y, c0.y);
        W1h[i][2] = __floats2half2_rn(a0.z, c0.z);
        W1h[i][3] = __floats2half2_rn(a0.w, c0.w);
        W1h[i][4] = __floats2half2_rn(a1.x, c1.x);
        W1h[i][5] = __floats2half2_rn(a1.y, c1.y);
        W1h[i][6] = __floats2half2_rn(a1.z, c1.z);
        W1h[i][7] = __floats2half2_rn(a1.w, c1.w);
    }
    float W2col[8];
    #pragma unroll
    for (int jj = 0; jj < 8; ++jj) W2col[jj] = W2[jj * 8 + r];
    float b1u[8];
    #pragma unroll
    for (int j = 0; j < 8; ++j) b1u[j] = sgpr_f(b1[j]);
    const float b2r = b2[r];
    const float wpA = Wp[2 * r], wpB = Wp[2 * r + 1];
    const float bp0 = sgpr_f(bp[0]);

    const int wb = (blockIdx.x * 4 + wave) * (8 * EW_EPT);

    #pragma unroll
    for (int t = 0; t < EW_EPT; ++t) {
        const int e = wb + t * 8 + o;

        const int2 sd = *reinterpret_cast<const int2*>(&eidx[2 * e]);
        const float2 e2 = *reinterpret_cast<const float2*>(&edges[(size_t)e * 16 + 2 * r]);

        uint4 q4u = *reinterpret_cast<const uint4*>(&xq[(size_t)sd.x * 64 + 8 * r]);
        uint4 k4u = *reinterpret_cast<const uint4*>(&xk[(size_t)sd.y * 64 + 8 * r]);

        float p = fmaf(e2.x, wpA, e2.y * wpB);
        p = oct_sum(p) + bp0;

        const __half2 p2 = __float2half2_rn(p);
        const __half2* qh = reinterpret_cast<const __half2*>(&q4u);
        const __half2* kh = reinterpret_cast<const __half2*>(&k4u);

        float part[8];
        #pragma unroll
        for (int jj = 0; jj < 8; ++jj) part[jj] = 0.f;
        #pragma unroll
        for (int i = 0; i < 4; ++i) {
            const __half2 d = relu_h2(__hadd2(__hsub2(kh[i], qh[i]), p2));
            #pragma unroll
            for (int jj = 0; jj < 8; ++jj)
                part[jj] = fdot2f(d, W1h[i][jj], part[jj]);
        }
        #pragma unroll
        for (int jj = 0; jj < 8; ++jj) part[jj] = oct_sum(part[jj]);

        float h2 = b2r;
        #pragma unroll
        for (int jj = 0; jj < 8; ++jj) {
            const float h1 = fmaxf(part[jj] + b1u[jj], 0.f);
            h2 = fmaf(h1, W2col[jj], h2);
        }

        // softmax without max-subtraction (|h2| << 88, f32-exp safe)
        const float ex = __expf(h2);
        const float sm = oct_sum(ex);
        const float w  = ex / sm;

        // quantize to u8 (*255, deferred 1/255 in node_accum's epilogue)
        const unsigned wu = (unsigned)__float2uint_rn(w * 255.f);
        unsigned word = wu << (8 * (r & 3));
        word |= (unsigned)dpp_mov_i32<0xB1>((int)word);   // quad or-combine
        word |= (unsigned)dpp_mov_i32<0x4E>((int)word);
        const unsigned other = (unsigned)dpp_mov_i32<0x141>((int)word); // other quad's word

        if (r == 0) {
            uint4 rec;
            rec.x = (unsigned)sd.x | ((unsigned)sd.y << 16);
            rec.y = word;    // w[0..3]
            rec.z = other;   // w[4..7]
            rec.w = __float_as_uint(p);
            rece[e] = rec;   // coalesced: 8 octets -> 128B contiguous
        }
        if (r == 1) atomicAdd(&cnt[sd.x], 1);
    }
}

// ---------------------------------------------------------------------------
// Scatter: ONE random 16B store per edge. src comes from the record.
// ---------------------------------------------------------------------------
__global__ __launch_bounds__(256) void scatter_kernel(
    const uint4* __restrict__ rece, int* __restrict__ cursor,
    uint4* __restrict__ reccsr)
{
    const int e = blockIdx.x * 256 + threadIdx.x;
    const uint4 rec = rece[e];
    const int src = (int)(rec.x & 0xFFFFu);
    const int pos = atomicAdd(&cursor[src], 1);
    reccsr[pos] = rec;
}

// ---------------------------------------------------------------------------
// Node accumulation, 2-wide unrolled (r22-proven): 16 lanes per node
// (2 sub-octets, alternate edges). Two records per main iteration with both
// xv gathers issued back-to-back. Weights u8 with deferred 1/255.
// ---------------------------------------------------------------------------
__global__ __launch_bounds__(256) void node_accum(
    const int* __restrict__ off, const uint4* __restrict__ reccsr,
    const __half* __restrict__ xv, float* __restrict__ out)
{
    const int tid  = threadIdx.x;
    const int lane = tid & 63;
    const int grp  = lane >> 4;
    const int sub  = (lane >> 3) & 1;
    const int r    = lane & 7;
    const int wave = tid >> 6;

    const int node = blockIdx.x * 16 + wave * 4 + grp;

    const int beg = off[node];
    const int end = off[node + 1];

    float acc[8];
    #pragma unroll
    for (int i = 0; i < 8; ++i) acc[i] = 0.f;

    int j = beg + sub;

    // main loop: two records per iteration, independent gather chains
    for (; j + 2 < end; j += 4) {
        const uint4 c0 = reccsr[j];
        const uint4 c1 = reccsr[j + 2];
        const int   dst0 = (int)(c0.x >> 16);
        const int   dst1 = (int)(c1.x >> 16);
        const float p0 = __uint_as_float(c0.w);
        const float p1 = __uint_as_float(c1.w);

        union { uint4 u; __half2 h[4]; } va, vb;
        va.u = *reinterpret_cast<const uint4*>(&xv[(size_t)dst0 * 64 + 8 * r]);
        vb.u = *reinterpret_cast<const uint4*>(&xv[(size_t)dst1 * 64 + 8 * r]);

        #pragma unroll
        for (int i = 0; i < 4; ++i) {
            const float2 fa = __half22float2(va.h[i]);
            const float2 fb = __half22float2(vb.h[i]);
            const float wa0 = (float)(((i < 2 ? c0.y : c0.z) >> (8 * ((2 * i) & 3))) & 255u);
            const float wa1 = (float)(((i < 2 ? c0.y : c0.z) >> (8 * ((2 * i + 1) & 3))) & 255u);
            const float wb0 = (float)(((i < 2 ? c1.y : c1.z) >> (8 * ((2 * i) & 3))) & 255u);
            const float wb1 = (float)(((i < 2 ? c1.y : c1.z) >> (8 * ((2 * i + 1) & 3))) & 255u);
            acc[2 * i]     = fmaf(fa.x + p0, wa0, acc[2 * i]);
            acc[2 * i + 1] = fmaf(fa.y + p0, wa1, acc[2 * i + 1]);
            acc[2 * i]     = fmaf(fb.x + p1, wb0, acc[2 * i]);
            acc[2 * i + 1] = fmaf(fb.y + p1, wb1, acc[2 * i + 1]);
        }
    }

    // tail: at most one record left for this sub-octet
    for (; j < end; j += 2) {
        const uint4 cur = reccsr[j];
        const int   dst = (int)(cur.x >> 16);
        const float p   = __uint_as_float(cur.w);

        union { uint4 u; __half2 h[4]; } v4;
        v4.u = *reinterpret_cast<const uint4*>(&xv[(size_t)dst * 64 + 8 * r]);

        #pragma unroll
        for (int i = 0; i < 4; ++i) {
            const float2 fv = __half22float2(v4.h[i]);
            const float w0 = (float)(((i < 2 ? cur.y : cur.z) >> (8 * ((2 * i) & 3))) & 255u);
            const float w1 = (float)(((i < 2 ? cur.y : cur.z) >> (8 * ((2 * i + 1) & 3))) & 255u);
            acc[2 * i]     = fmaf(fv.x + p, w0, acc[2 * i]);
            acc[2 * i + 1] = fmaf(fv.y + p, w1, acc[2 * i + 1]);
        }
    }

    #pragma unroll
    for (int i = 0; i < 8; ++i)
        acc[i] += __shfl_xor(acc[i], 8);

    if (sub == 0) {
        const float c = 1.f / 255.f;
        float* orow = &out[(size_t)node * 64 + 8 * r];
        *reinterpret_cast<float4*>(orow) =
            make_float4(acc[0] * c, acc[1] * c, acc[2] * c, acc[3] * c);
        *reinterpret_cast<float4*>(orow + 4) =
            make_float4(acc[4] * c, acc[5] * c, acc[6] * c, acc[7] * c);
    }
}

extern "C" void kernel_launch(void* const* d_in, const int* in_sizes, int n_in,
                              void* d_out, int out_size, void* d_ws, size_t ws_size,
                              hipStream_t stream) {
    const float* q     = (const float*)d_in[0];
    const float* k     = (const float*)d_in[1];
    const float* v     = (const float*)d_in[2];
    const float* edges = (const float*)d_in[3];
    const int*   eidx  = (const int*)d_in[4];
    const float* Wq    = (const float*)d_in[5];
    const float* bq    = (const float*)d_in[6];
    const float* Wk    = (const float*)d_in[7];
    const float* bk    = (const float*)d_in[8];
    const float* Wv    = (const float*)d_in[9];
    const float* bv    = (const float*)d_in[10];
    const float* Wp    = (const float*)d_in[11];
    const float* bp    = (const float*)d_in[12];
    const float* W1    = (const float*)d_in[13];
    const float* b1    = (const float*)d_in[14];
    const float* W2    = (const float*)d_in[15];
    const float* b2    = (const float*)d_in[16];
    float* out = (float*)d_out;

    // workspace layout
    char* ws = (char*)d_ws;
    __half* xq = (__half*)ws;          ws += (size_t)N_NODES * 64 * sizeof(__half);
    __half* xk = (__half*)ws;          ws += (size_t)N_NODES * 64 * sizeof(__half);
    __half* xv = (__half*)ws;          ws += (size_t)N_NODES * 64 * sizeof(__half);
    int* cnt  = (int*)ws;              ws += (size_t)(N_NODES + 64) * sizeof(int);
    int* off  = (int*)ws;              ws += (size_t)(N_NODES + 64) * sizeof(int);
    int* bsum = (int*)ws;              ws += (size_t)64 * sizeof(int);
    uint4* rece   = (uint4*)ws;        ws += (size_t)E_EDGES * sizeof(uint4);   // 12.8 MB
    uint4* reccsr = (uint4*)ws;        ws += (size_t)E_EDGES * sizeof(uint4);   // 12.8 MB

    // proj also zeroes cnt (memset dispatch removed)
    proj_kernel<<<dim3((N_NODES + 63) / 64), dim3(256), 0, stream>>>(
        q, k, v, Wq, bq, Wk, bk, Wv, bv, xq, xk, xv, cnt);

    edge_weights<<<dim3(E_EDGES / (32 * EW_EPT)), dim3(256), 0, stream>>>(
        eidx, edges, Wp, bp, W1, b1, W2, b2, xq, xk, cnt, rece);

    scan_sums<<<dim3(SCAN_NBLK), dim3(256), 0, stream>>>(cnt, bsum);
    scan_final<<<dim3(SCAN_NBLK), dim3(256), 0, stream>>>(cnt, bsum, off);

    scatter_kernel<<<dim3(E_EDGES / 256), dim3(256), 0, stream>>>(
        rece, cnt, reccsr);

    node_accum<<<dim3(N_NODES / 16), dim3(256), 0, stream>>>(
        off, reccsr, xv, out);
}